// Round 7
// baseline (728.860 us; speedup 1.0000x reference)
//
#include <hip/hip_runtime.h>
#include <stdint.h>
#include <stddef.h>

typedef _Float16 f16;
typedef _Float16 half8 __attribute__((ext_vector_type(8)));
typedef float f32x4 __attribute__((ext_vector_type(4)));

constexpr int kB = 4, kSQ = 512, kSK = 1024, kH = 1024, kHeads = 16, kE = 8, kDFF = 4096;
constexpr int kTok = kB * kSQ;  // 2048 gen tokens

// async global->LDS, 16B per lane; LDS dest must be wave-uniform base + lane*16
__device__ __forceinline__ void g2l16(const f16* g, f16* l) {
  __builtin_amdgcn_global_load_lds((const __attribute__((address_space(1))) uint32_t*)g,
                                   (__attribute__((address_space(3))) uint32_t*)l, 16, 0, 0);
}

// counted vmcnt wait (T4): leave N VMEM instructions in flight
template <int N>
__device__ __forceinline__ void vmwait() {
  asm volatile("s_waitcnt vmcnt(%0)" :: "i"(N) : "memory");
}

// ---------------- transpose + fp32->fp16: dst[C][R] = (f16)src[R][C], batched over z
__global__ __launch_bounds__(256) void tr_f2h(const float* __restrict__ src,
                                              f16* __restrict__ dst, int R, int C) {
  __shared__ float t[32][33];
  long zo = (long)blockIdx.z * R * C;
  int r0 = blockIdx.y * 32, c0 = blockIdx.x * 32;
  int tr = threadIdx.x >> 3, tc = (threadIdx.x & 7) << 2;
  float4 v = *(const float4*)(src + zo + (long)(r0 + tr) * C + c0 + tc);
  t[tr][tc] = v.x; t[tr][tc + 1] = v.y; t[tr][tc + 2] = v.z; t[tr][tc + 3] = v.w;
  __syncthreads();
  union { f16 h[4]; uint2 u; } o;
  o.h[0] = (f16)t[tc + 0][tr]; o.h[1] = (f16)t[tc + 1][tr];
  o.h[2] = (f16)t[tc + 2][tr]; o.h[3] = (f16)t[tc + 3][tr];
  *(uint2*)(dst + zo + (long)(c0 + tr) * R + r0 + tc) = o.u;
}

// ---------------- LayerNorm over H=1024, one block (256 thr) per row --------
__global__ __launch_bounds__(256) void ln_kernel(const float* __restrict__ x,
                                                 const float* __restrict__ g,
                                                 const float* __restrict__ b,
                                                 f16* __restrict__ oh, float* __restrict__ of,
                                                 int rows) {
  int row = blockIdx.x;
  if (row >= rows) return;
  int tid = threadIdx.x;
  const float* xr = x + (long)row * kH;
  float4 v = *(const float4*)(xr + tid * 4);
  float s = v.x + v.y + v.z + v.w;
  float s2 = v.x * v.x + v.y * v.y + v.z * v.z + v.w * v.w;
  __shared__ float red[8];
  for (int o = 32; o; o >>= 1) { s += __shfl_down(s, o); s2 += __shfl_down(s2, o); }
  int wv = tid >> 6, lane = tid & 63;
  if (lane == 0) { red[wv] = s; red[4 + wv] = s2; }
  __syncthreads();
  if (tid == 0) {
    red[0] = red[0] + red[1] + red[2] + red[3];
    red[4] = red[4] + red[5] + red[6] + red[7];
  }
  __syncthreads();
  float mean = red[0] * (1.0f / kH);
  float var = red[4] * (1.0f / kH) - mean * mean;
  float rs = rsqrtf(var + 1e-6f);
  float4 gv = *(const float4*)(g + tid * 4);
  float4 bv = *(const float4*)(b + tid * 4);
  float y0 = (v.x - mean) * rs * gv.x + bv.x;
  float y1 = (v.y - mean) * rs * gv.y + bv.y;
  float y2 = (v.z - mean) * rs * gv.z + bv.z;
  float y3 = (v.w - mean) * rs * gv.w + bv.w;
  long base = (long)row * kH + tid * 4;
  if (oh) {
    union { f16 h[4]; uint2 u; } o;
    o.h[0] = (f16)y0; o.h[1] = (f16)y1; o.h[2] = (f16)y2; o.h[3] = (f16)y3;
    *(uint2*)(oh + base) = o.u;
  }
  if (of) { float4 o4 = {y0, y1, y2, y3}; *(float4*)(of + base) = o4; }
}

__global__ void zero_kernel(int* __restrict__ p, int n) {
  int i = blockIdx.x * blockDim.x + threadIdx.x;
  if (i < n) p[i] = 0;
}

// ---------------- router: fp32 logits, first-index argmax, bucket tokens ----
__global__ __launch_bounds__(64) void router_kernel(const float* __restrict__ ca,
                                                    const float* __restrict__ gw,
                                                    const float* __restrict__ gb,
                                                    int* __restrict__ cursors,
                                                    int* __restrict__ list,
                                                    int* __restrict__ eid) {
  int t = blockIdx.x;
  int lane = threadIdx.x;
  const float* x = ca + (long)t * kH;
  float acc[kE];
#pragma unroll
  for (int e = 0; e < kE; e++) acc[e] = 0.0f;
  for (int h = lane; h < kH; h += 64) {
    float xv = x[h];
    const float* gr = gw + (long)h * kE;
#pragma unroll
    for (int e = 0; e < kE; e++) acc[e] += xv * gr[e];
  }
#pragma unroll
  for (int e = 0; e < kE; e++)
    for (int o = 32; o; o >>= 1) acc[e] += __shfl_down(acc[e], o);
  if (lane == 0) {
    int best = 0;
    float bv = acc[0] + gb[0];
    for (int e = 1; e < kE; e++) {
      float v = acc[e] + gb[e];
      if (v > bv) { bv = v; best = e; }  // strict > == first-index argmax
    }
    int slot = atomicAdd(&cursors[best], 1);
    list[best * kTok + slot] = t;
    eid[t] = best;
  }
}

// ---------------- FFN2 reduce: out = sum(part[0..3]) + b2[eid] + lnca --------
__global__ __launch_bounds__(256) void ffn2_reduce(const float* __restrict__ part,
                                                   const float* __restrict__ lnca,
                                                   const float* __restrict__ b2,
                                                   const int* __restrict__ eid,
                                                   float* __restrict__ out) {
  int t = blockIdx.x;
  int i = threadIdx.x * 4;
  int e = eid[t];
  long idx = (long)t * kH + i;
  float4 p0 = *(const float4*)(part + idx);
  float4 p1 = *(const float4*)(part + (long)kTok * kH + idx);
  float4 p2 = *(const float4*)(part + 2L * kTok * kH + idx);
  float4 p3 = *(const float4*)(part + 3L * kTok * kH + idx);
  float4 r  = *(const float4*)(lnca + idx);
  float4 bb = *(const float4*)(b2 + (long)e * kH + i);
  float4 o = {p0.x + p1.x + p2.x + p3.x + r.x + bb.x,
              p0.y + p1.y + p2.y + p3.y + r.y + bb.y,
              p0.z + p1.z + p2.z + p3.z + r.z + bb.z,
              p0.w + p1.w + p2.w + p3.w + r.w + bb.w};
  *(float4*)(out + idx) = o;
}

// ---------------- fused flash attention ----------------
// K/V staged row-contiguous (8 lanes per 128B row), XOR-swizzled source+read.
__global__ __launch_bounds__(256) void flash_kernel(const f16* __restrict__ q,
                                                    const f16* __restrict__ k,
                                                    const f16* __restrict__ v_t,
                                                    const float* __restrict__ mask,
                                                    f16* __restrict__ ctx) {
  __shared__ f16 Ks[64 * 64];
  __shared__ f16 Vs[64 * 64];
  __shared__ f16 Ps[4][16][72];  // pitch 72 (144B) breaks write conflicts
  int qt = blockIdx.x;
  int bh = blockIdx.y;
  int b = bh >> 4;
  int ho = (bh & 15) * 64;
  int tid = threadIdx.x, lane = tid & 63, wave = tid >> 6;
  int quad = lane >> 4, lo = lane & 15;

  long qg = ((long)b * kSQ + qt * 64 + wave * 16 + lo) * kH + ho;
  half8 aq0 = *(const half8*)(q + qg + quad * 8);
  half8 aq1 = *(const half8*)(q + qg + 32 + quad * 8);

  // staging: chunk c = s*256+tid -> row = c>>3, octet = (c&7) ^ (row&7)  [swizzled source]
  int srow = tid >> 3;                       // 0..31 within group
  int soct = (tid & 7) ^ (srow & 7);         // swizzled k/sk octet
  const f16* ksrc[2];
  const f16* vsrc[2];
#pragma unroll
  for (int s = 0; s < 2; s++) {
    int r = s * 32 + srow;
    ksrc[s] = k + ((long)b * kSK + r) * kH + ho + soct * 8;       // row = key
    vsrc[s] = v_t + ((long)bh * 64 + r) * kSK + soct * 8;         // row = d
  }
  const float* maskp = mask + ((long)b * kSQ + qt * 64 + wave * 16 + quad * 4) * kSK;

  float m_s[4] = {-1e30f, -1e30f, -1e30f, -1e30f};
  float l_s[4] = {0.f, 0.f, 0.f, 0.f};
  f32x4 O[4] = {};

  for (int kt = 0; kt < kSK / 64; kt++) {
    int sk0 = kt * 64;
#pragma unroll
    for (int s = 0; s < 2; s++) g2l16(ksrc[s] + (long)sk0 * kH, &Ks[(s * 256 + tid) * 8]);
#pragma unroll
    for (int s = 0; s < 2; s++) g2l16(vsrc[s] + sk0, &Vs[(s * 256 + tid) * 8]);
    __syncthreads();
    f32x4 sf[4] = {};
#pragma unroll
    for (int nt = 0; nt < 4; nt++) {
      int key = nt * 16 + lo;
      half8 bk0 = *(const half8*)&Ks[key * 64 + (((0 * 4 + quad)) ^ (key & 7)) * 8];
      half8 bk1 = *(const half8*)&Ks[key * 64 + (((1 * 4 + quad)) ^ (key & 7)) * 8];
      sf[nt] = __builtin_amdgcn_mfma_f32_16x16x32_f16(aq0, bk0, sf[nt], 0, 0, 0);
      sf[nt] = __builtin_amdgcn_mfma_f32_16x16x32_f16(aq1, bk1, sf[nt], 0, 0, 0);
    }
#pragma unroll
    for (int r = 0; r < 4; r++)
#pragma unroll
      for (int nt = 0; nt < 4; nt++)
        sf[nt][r] += maskp[(long)r * kSK + sk0 + nt * 16 + lo];
#pragma unroll
    for (int r = 0; r < 4; r++) {
      float mx = fmaxf(fmaxf(sf[0][r], sf[1][r]), fmaxf(sf[2][r], sf[3][r]));
      mx = fmaxf(mx, __shfl_xor(mx, 1));
      mx = fmaxf(mx, __shfl_xor(mx, 2));
      mx = fmaxf(mx, __shfl_xor(mx, 4));
      mx = fmaxf(mx, __shfl_xor(mx, 8));
      float m_new = fmaxf(m_s[r], mx);
      float alpha = __expf(m_s[r] - m_new);
      m_s[r] = m_new;
      float p0 = __expf(sf[0][r] - m_new), p1 = __expf(sf[1][r] - m_new);
      float p2 = __expf(sf[2][r] - m_new), p3 = __expf(sf[3][r] - m_new);
      float rs = p0 + p1 + p2 + p3;
      rs += __shfl_xor(rs, 1);
      rs += __shfl_xor(rs, 2);
      rs += __shfl_xor(rs, 4);
      rs += __shfl_xor(rs, 8);
      l_s[r] = l_s[r] * alpha + rs;
#pragma unroll
      for (int nt = 0; nt < 4; nt++) O[nt][r] *= alpha;
      Ps[wave][quad * 4 + r][0 * 16 + lo] = (f16)p0;
      Ps[wave][quad * 4 + r][1 * 16 + lo] = (f16)p1;
      Ps[wave][quad * 4 + r][2 * 16 + lo] = (f16)p2;
      Ps[wave][quad * 4 + r][3 * 16 + lo] = (f16)p3;
    }
    half8 ap0 = *(const half8*)&Ps[wave][lo][quad * 8];
    half8 ap1 = *(const half8*)&Ps[wave][lo][32 + quad * 8];
#pragma unroll
    for (int nt = 0; nt < 4; nt++) {
      int d = nt * 16 + lo;
      half8 bv0 = *(const half8*)&Vs[d * 64 + (((0 * 4 + quad)) ^ (d & 7)) * 8];
      half8 bv1 = *(const half8*)&Vs[d * 64 + (((1 * 4 + quad)) ^ (d & 7)) * 8];
      O[nt] = __builtin_amdgcn_mfma_f32_16x16x32_f16(ap0, bv0, O[nt], 0, 0, 0);
      O[nt] = __builtin_amdgcn_mfma_f32_16x16x32_f16(ap1, bv1, O[nt], 0, 0, 0);
    }
    __syncthreads();
  }
#pragma unroll
  for (int r = 0; r < 4; r++) {
    float inv = 1.0f / l_s[r];
    long row = (long)b * kSQ + qt * 64 + wave * 16 + quad * 4 + r;
#pragma unroll
    for (int nt = 0; nt < 4; nt++)
      ctx[row * kH + ho + nt * 16 + lo] = (f16)(O[nt][r] * inv);
  }
}

// ---------------- tiled fp16 MFMA GEMM, BK=64, ring-3 counted-vmcnt staging --
// C[M,N] = epilogue(A[M,K] @ B[N,K]^T); B is [N][K] k-contiguous.
// Row-contiguous staging (8 lanes per 128B row), XOR-swizzled source + reads.
// Ring-3: 2 K-tiles in flight across barriers; vmcnt(PER) never drains mid-loop.
struct GemmP {
  const f16* A; long a_row, a_z1, a_z2;
  const f16* Bm; long b_nstr, b_z1, b_z2;
  float* Cf; f16* Ch; long c_row, c_z1, c_z2, c_split; int c_tr;
  const float* bias; long bias_z;
  const float* res; long res_row, res_z1, res_z2;
  float alpha; int gelu; int ksplit;
  int M, N, K, zdiv;
  const int* glist; const int* cnt;  // expert-gather mode: z = expert
};

template <int BM, int BN>
__device__ __forceinline__ void gemm_body(const GemmP& p, int bx, int by, int bz,
                                          f16* A0, f16* A1, f16* A2,
                                          f16* B0, f16* B1, f16* B2) {
  constexpr int FM = BM / 32, FN = BN / 32;
  constexpr int PER = BM / 32 + BN / 32;  // g2l16 instrs per stage per thread
  int z = bz;
  int kb = 0, kEnd = p.K, ks = 0;
  if (p.ksplit > 1) {
    int kc = p.K / p.ksplit;
    ks = z % p.ksplit;
    kb = ks * kc;
    kEnd = kb + kc;
    z /= p.ksplit;
  }
  long aoff = 0, boff = 0, coff = 0, roff = 0, biasoff = 0;
  const int* gl = nullptr;
  int Meff = p.M;
  if (p.glist) {
    Meff = p.cnt[z];
    gl = p.glist + (long)z * kTok;
    boff = (long)z * p.b_z2;
    biasoff = (long)z * p.bias_z;
  } else {
    int z1 = z / p.zdiv, z2 = z % p.zdiv;
    aoff = (long)z1 * p.a_z1 + (long)z2 * p.a_z2;
    boff = (long)z1 * p.b_z1 + (long)z2 * p.b_z2;
    coff = (long)z1 * p.c_z1 + (long)z2 * p.c_z2;
    roff = (long)z1 * p.res_z1 + (long)z2 * p.res_z2;
  }
  coff += (long)ks * p.c_split;
  int m0 = by * BM;
  if (m0 >= Meff) return;
  int n0 = bx * BN;
  int tid = threadIdx.x, lane = tid & 63, wave = tid >> 6;
  int wm = (wave & 1) * (BM / 2), wn = (wave >> 1) * (BN / 2);
  int q = lane >> 4, lo = lane & 15;

  // row-contiguous staging: chunk c = s*256+tid -> row = s*32 + (tid>>3),
  // source k-octet = (tid&7) ^ (row&7); LDS dest linear -> [row][slot].
  int srow = tid >> 3;
  int soct = (tid & 7) ^ (srow & 7);
  const f16* asrc[BM / 32];
  const f16* bsrc[BN / 32];
#pragma unroll
  for (int s = 0; s < BM / 32; s++) {
    int row = m0 + s * 32 + srow;
    if (gl) row = gl[row < Meff ? row : Meff - 1];  // clamp: garbage rows never stored
    asrc[s] = p.A + aoff + (long)row * p.a_row + soct * 8;
  }
#pragma unroll
  for (int s = 0; s < BN / 32; s++)
    bsrc[s] = p.Bm + boff + (long)(n0 + s * 32 + srow) * p.b_nstr + soct * 8;

  f32x4 acc[FM][FN] = {};

  auto stage = [&](f16* Ad, f16* Bd, int k0) {
#pragma unroll
    for (int s = 0; s < BM / 32; s++) g2l16(asrc[s] + k0, &Ad[(s * 256 + tid) * 8]);
#pragma unroll
    for (int s = 0; s < BN / 32; s++) g2l16(bsrc[s] + k0, &Bd[(s * 256 + tid) * 8]);
  };
  auto compute = [&](const f16* As, const f16* Bs) {
    half8 af[2][FM], bf[2][FN];
#pragma unroll
    for (int kk = 0; kk < 2; kk++) {
#pragma unroll
      for (int i = 0; i < FM; i++) {
        int r = wm + i * 16 + lo;
        af[kk][i] = *(const half8*)&As[r * 64 + ((kk * 4 + q) ^ (r & 7)) * 8];
      }
#pragma unroll
      for (int j = 0; j < FN; j++) {
        int n = wn + j * 16 + lo;
        bf[kk][j] = *(const half8*)&Bs[n * 64 + ((kk * 4 + q) ^ (n & 7)) * 8];
      }
    }
#pragma unroll
    for (int kk = 0; kk < 2; kk++)
#pragma unroll
      for (int i = 0; i < FM; i++)
#pragma unroll
        for (int j = 0; j < FN; j++)
          acc[i][j] = __builtin_amdgcn_mfma_f32_16x16x32_f16(af[kk][i], bf[kk][j], acc[i][j], 0, 0, 0);
  };

  // ring-3 pipeline: tiles i, i+1 in flight; one barrier/step.
  // vmcnt(PER) at iter i completes tile i while tile i+1 stays in flight.
  int nt = (kEnd - kb) / 64;
  stage(A0, B0, kb);
  if (nt > 1) stage(A1, B1, kb + 64);
  f16 *Ac = A0, *An = A1, *Af = A2;
  f16 *Bc = B0, *Bn = B1, *Bf = B2;
  for (int i = 0; i < nt; i++) {
    if (i + 1 < nt) vmwait<PER>(); else vmwait<0>();
    __builtin_amdgcn_sched_barrier(0);
    __builtin_amdgcn_s_barrier();
    if (i + 2 < nt) stage(Af, Bf, kb + (i + 2) * 64);
    compute(Ac, Bc);
    f16* t;
    t = Ac; Ac = An; An = Af; Af = t;
    t = Bc; Bc = Bn; Bn = Bf; Bf = t;
  }

#pragma unroll
  for (int i = 0; i < FM; i++) {
#pragma unroll
    for (int j = 0; j < FN; j++) {
      int col = n0 + wn + j * 16 + lo;
      if (p.c_tr) {  // transposed f16 store: 4 consecutive rows -> one 8B store
        int row0 = m0 + wm + i * 16 + q * 4;
        union { f16 h[4]; uint2 u; } o;
#pragma unroll
        for (int r = 0; r < 4; r++) {
          float v = acc[i][j][r];
          if (p.bias) v += p.bias[biasoff + col];
          v *= p.alpha;
          o.h[r] = (f16)v;
        }
        *(uint2*)&p.Ch[coff + (long)col * p.c_row + row0] = o.u;
      } else {
#pragma unroll
        for (int r = 0; r < 4; r++) {
          int row = m0 + wm + i * 16 + q * 4 + r;
          if (row < Meff) {
            long rr = gl ? (long)gl[row] : (long)row;
            float v = acc[i][j][r];
            if (p.bias) v += p.bias[biasoff + col];
            v *= p.alpha;
            if (p.res) v += p.res[roff + rr * p.res_row + col];
            if (p.gelu) v = 0.5f * v * (1.0f + erff(v * 0.70710678118654752f));
            long ci = coff + rr * p.c_row + col;
            if (p.Cf) p.Cf[ci] = v;
            else p.Ch[ci] = (f16)v;
          }
        }
      }
    }
  }
}

template <int BM, int BN>
__global__ __launch_bounds__(256) void gemm_t(GemmP p) {
  __shared__ f16 A0[BM * 64], A1[BM * 64], A2[BM * 64];
  __shared__ f16 B0[BN * 64], B1[BN * 64], B2[BN * 64];
  gemm_body<BM, BN>(p, blockIdx.x, blockIdx.y, blockIdx.z, A0, A1, A2, B0, B1, B2);
}

// fused Q/K/V projections: one flat grid, block ranges per sub-GEMM (128x64 tiles)
struct Multi3P {
  GemmP g0, g1, g2;
  int n0, n1;
  int gx0, gy0, gx1, gy1, gx2, gy2;
};

__global__ __launch_bounds__(256) void gemm_qkv(Multi3P mp) {
  __shared__ f16 A0[128 * 64], A1[128 * 64], A2[128 * 64];
  __shared__ f16 B0[64 * 64], B1[64 * 64], B2[64 * 64];
  int fb = blockIdx.x;
  if (fb < mp.n0) {
    gemm_body<128, 64>(mp.g0, fb % mp.gx0, (fb / mp.gx0) % mp.gy0, fb / (mp.gx0 * mp.gy0),
                       A0, A1, A2, B0, B1, B2);
    return;
  }
  fb -= mp.n0;
  if (fb < mp.n1) {
    gemm_body<128, 64>(mp.g1, fb % mp.gx1, (fb / mp.gx1) % mp.gy1, fb / (mp.gx1 * mp.gy1),
                       A0, A1, A2, B0, B1, B2);
    return;
  }
  fb -= mp.n1;
  gemm_body<128, 64>(mp.g2, fb % mp.gx2, (fb / mp.gx2) % mp.gy2, fb / (mp.gx2 * mp.gy2),
                     A0, A1, A2, B0, B1, B2);
}

extern "C" void kernel_launch(void* const* d_in, const int* in_sizes, int n_in,
                              void* d_out, int out_size, void* d_ws, size_t ws_size,
                              hipStream_t stream) {
  const float* concated = (const float*)d_in[0];
  const float* gen      = (const float*)d_in[1];
  const float* mask     = (const float*)d_in[2];
  const float* ln_g     = (const float*)d_in[3];
  const float* ln_b     = (const float*)d_in[4];
  const float* wq = (const float*)d_in[5];  const float* bq = (const float*)d_in[6];
  const float* wk = (const float*)d_in[7];  const float* bk = (const float*)d_in[8];
  const float* wv = (const float*)d_in[9];  const float* bv = (const float*)d_in[10];
  const float* wo = (const float*)d_in[11]; const float* bo = (const float*)d_in[12];
  const float* gw = (const float*)d_in[13]; const float* gb = (const float*)d_in[14];
  const float* w1 = (const float*)d_in[15]; const float* b1 = (const float*)d_in[16];
  const float* w2 = (const float*)d_in[17]; const float* b2 = (const float*)d_in[18];
  float* out = (float*)d_out;

  size_t off = 0;
  auto alloc = [&](size_t bytes) -> void* {
    void* p = (char*)d_ws + off;
    off += (bytes + 255) & ~(size_t)255;
    return p;
  };
  f16* wq_t  = (f16*)alloc((size_t)kH * kH * 2);       // [N][K]
  f16* wk_t  = (f16*)alloc((size_t)kH * kH * 2);
  f16* wv_t  = (f16*)alloc((size_t)kH * kH * 2);
  f16* wo_t  = (f16*)alloc((size_t)kH * kH * 2);
  f16* w1_t  = (f16*)alloc((size_t)kE * kH * kDFF * 2);  // [E][DFF][H]
  f16* w2_t  = (f16*)alloc((size_t)kE * kDFF * kH * 2);  // [E][H][DFF]
  f16* lnc_h = (f16*)alloc((size_t)kB * kSK * kH * 2);
  f16* lng_h = (f16*)alloc((size_t)kTok * kH * 2);
  f16* q_h   = (f16*)alloc((size_t)kTok * kH * 2);
  f16* k_h   = (f16*)alloc((size_t)kB * kSK * kH * 2);
  f16* v_t   = (f16*)alloc((size_t)kB * kSK * kH * 2);   // [b][h][d][sk]
  f16* ctx_h = (f16*)alloc((size_t)kTok * kH * 2);
  float* ca_f   = (float*)alloc((size_t)kTok * kH * 4);
  float* lnca_f = (float*)alloc((size_t)kTok * kH * 4);
  f16* lnca_h   = (f16*)alloc((size_t)kTok * kH * 2);
  f16* h1_h     = (f16*)alloc((size_t)kTok * kDFF * 2);
  float* part_f = (float*)alloc((size_t)4 * kTok * kH * 4);
  int* cnt_d    = (int*)alloc(kE * 4);
  int* list_d   = (int*)alloc((size_t)kE * kTok * 4);
  int* eid_d    = (int*)alloc((size_t)kTok * 4);

  // ---- weight transpose-convert fp32 [K][N] -> fp16 [N][K] ----
  tr_f2h<<<dim3(32, 32, 1), 256, 0, stream>>>(wq, wq_t, kH, kH);
  tr_f2h<<<dim3(32, 32, 1), 256, 0, stream>>>(wk, wk_t, kH, kH);
  tr_f2h<<<dim3(32, 32, 1), 256, 0, stream>>>(wv, wv_t, kH, kH);
  tr_f2h<<<dim3(32, 32, 1), 256, 0, stream>>>(wo, wo_t, kH, kH);
  tr_f2h<<<dim3(kDFF / 32, kH / 32, kE), 256, 0, stream>>>(w1, w1_t, kH, kDFF);
  tr_f2h<<<dim3(kH / 32, kDFF / 32, kE), 256, 0, stream>>>(w2, w2_t, kDFF, kH);

  // ---- LayerNorms of inputs ----
  ln_kernel<<<kB * kSK, 256, 0, stream>>>(concated, ln_g, ln_b, lnc_h, nullptr, kB * kSK);
  ln_kernel<<<kTok, 256, 0, stream>>>(gen, ln_g, ln_b, lng_h, nullptr, kTok);

  // ---- fused Q/K/V projections (one launch, 1280 blocks at 128x64) ----
  {
    Multi3P mp{};
    GemmP& pq = mp.g0;
    pq.A = lng_h; pq.a_row = kH; pq.Bm = wq_t; pq.b_nstr = kH;
    pq.Ch = q_h; pq.c_row = kH; pq.bias = bq; pq.alpha = 0.125f;
    pq.M = kTok; pq.N = kH; pq.K = kH; pq.zdiv = 1;
    GemmP& pk = mp.g1;
    pk.A = lnc_h; pk.a_row = kH; pk.Bm = wk_t; pk.b_nstr = kH;
    pk.Ch = k_h; pk.c_row = kH; pk.bias = bk; pk.alpha = 1.0f;
    pk.M = kB * kSK; pk.N = kH; pk.K = kH; pk.zdiv = 1;
    GemmP& pv = mp.g2;
    pv.A = lnc_h; pv.a_row = kH; pv.a_z1 = (long)kSK * kH;
    pv.Bm = wv_t; pv.b_nstr = kH;
    pv.Ch = v_t; pv.c_row = kSK; pv.c_z1 = (long)kH * kSK; pv.c_tr = 1;
    pv.bias = bv; pv.alpha = 1.0f;
    pv.M = kSK; pv.N = kH; pv.K = kH; pv.zdiv = 1;
    mp.gx0 = kH / 64; mp.gy0 = kTok / 128;        mp.n0 = mp.gx0 * mp.gy0;       // 256
    mp.gx1 = kH / 64; mp.gy1 = (kB * kSK) / 128;  mp.n1 = mp.gx1 * mp.gy1;       // 512
    mp.gx2 = kH / 64; mp.gy2 = kSK / 128;                                         // x8, z=4
    int ntot = mp.n0 + mp.n1 + mp.gx2 * mp.gy2 * kB;                              // 1280
    gemm_qkv<<<dim3(ntot), 256, 0, stream>>>(mp);
  }
  // ---- fused flash attention -> ctx_h ----
  flash_kernel<<<dim3(kSQ / 64, kB * kHeads), 256, 0, stream>>>(q_h, k_h, v_t, mask, ctx_h);
  // ---- ca_out = ctx @ wo^T + bo + gen (fp32 out) ----
  {
    GemmP p{}; p.A = ctx_h; p.a_row = kH;
    p.Bm = wo_t; p.b_nstr = kH;
    p.Cf = ca_f; p.c_row = kH; p.bias = bo;
    p.res = gen; p.res_row = kH;
    p.alpha = 1.0f; p.M = kTok; p.N = kH; p.K = kH; p.zdiv = 1;
    gemm_t<128, 64><<<dim3(kH / 64, kTok / 128, 1), 256, 0, stream>>>(p);
  }
  // ---- ln_ca (fp32 + fp16) ----
  ln_kernel<<<kTok, 256, 0, stream>>>(ca_f, ln_g, ln_b, lnca_h, lnca_f, kTok);
  // ---- router + expert bucketing ----
  zero_kernel<<<1, 64, 0, stream>>>(cnt_d, kE);
  router_kernel<<<kTok, 64, 0, stream>>>(ca_f, gw, gb, cnt_d, list_d, eid_d);
  // ---- FFN1: h1 = gelu(ln_ca @ w1[e] + b1[e]) ; 128x64 tile ----
  {
    GemmP p{}; p.A = lnca_h; p.a_row = kH;
    p.Bm = w1_t; p.b_nstr = kH; p.b_z2 = (long)kH * kDFF;
    p.Ch = h1_h; p.c_row = kDFF; p.bias = b1; p.bias_z = kDFF;
    p.alpha = 1.0f; p.gelu = 1; p.M = kTok; p.N = kDFF; p.K = kH; p.zdiv = 1;
    p.glist = list_d; p.cnt = cnt_d;
    gemm_t<128, 64><<<dim3(kDFF / 64, kTok / 128, kE), 256, 0, stream>>>(p);
  }
  // ---- FFN2: part[s] = h1 @ w2[e] (split-K x4, fp32 partials, no atomics) ----
  {
    GemmP p{}; p.A = h1_h; p.a_row = kDFF;
    p.Bm = w2_t; p.b_nstr = kDFF; p.b_z2 = (long)kDFF * kH;
    p.Cf = part_f; p.c_row = kH; p.c_split = (long)kTok * kH;
    p.alpha = 1.0f; p.ksplit = 4;
    p.M = kTok; p.N = kH; p.K = kDFF; p.zdiv = 1;
    p.glist = list_d; p.cnt = cnt_d;
    gemm_t<128, 64><<<dim3(kH / 64, kTok / 128, kE * 4), 256, 0, stream>>>(p);
  }
  // ---- reduce: out = sum(part) + b2[eid] + lnca ----
  ffn2_reduce<<<kTok, 256, 0, stream>>>(part_f, lnca_f, b2, eid_d, out);
}

// Round 8
// 718.992 us; speedup vs baseline: 1.0137x; 1.0137x over previous
//
#include <hip/hip_runtime.h>
#include <stdint.h>
#include <stddef.h>

typedef _Float16 f16;
typedef _Float16 half8 __attribute__((ext_vector_type(8)));
typedef float f32x4 __attribute__((ext_vector_type(4)));

constexpr int kB = 4, kSQ = 512, kSK = 1024, kH = 1024, kHeads = 16, kE = 8, kDFF = 4096;
constexpr int kTok = kB * kSQ;  // 2048 gen tokens

// async global->LDS, 16B per lane; LDS dest must be wave-uniform base + lane*16
__device__ __forceinline__ void g2l16(const f16* g, f16* l) {
  __builtin_amdgcn_global_load_lds((const __attribute__((address_space(1))) uint32_t*)g,
                                   (__attribute__((address_space(3))) uint32_t*)l, 16, 0, 0);
}

// ---------------- transpose + fp32->fp16: dst[C][R] = (f16)src[R][C], batched over z
__global__ __launch_bounds__(256) void tr_f2h(const float* __restrict__ src,
                                              f16* __restrict__ dst, int R, int C) {
  __shared__ float t[32][33];
  long zo = (long)blockIdx.z * R * C;
  int r0 = blockIdx.y * 32, c0 = blockIdx.x * 32;
  int tr = threadIdx.x >> 3, tc = (threadIdx.x & 7) << 2;
  float4 v = *(const float4*)(src + zo + (long)(r0 + tr) * C + c0 + tc);
  t[tr][tc] = v.x; t[tr][tc + 1] = v.y; t[tr][tc + 2] = v.z; t[tr][tc + 3] = v.w;
  __syncthreads();
  union { f16 h[4]; uint2 u; } o;
  o.h[0] = (f16)t[tc + 0][tr]; o.h[1] = (f16)t[tc + 1][tr];
  o.h[2] = (f16)t[tc + 2][tr]; o.h[3] = (f16)t[tc + 3][tr];
  *(uint2*)(dst + zo + (long)(c0 + tr) * R + r0 + tc) = o.u;
}

// ---------------- LayerNorm over H=1024, one block (256 thr) per row --------
__global__ __launch_bounds__(256) void ln_kernel(const float* __restrict__ x,
                                                 const float* __restrict__ g,
                                                 const float* __restrict__ b,
                                                 f16* __restrict__ oh, float* __restrict__ of,
                                                 int rows) {
  int row = blockIdx.x;
  if (row >= rows) return;
  int tid = threadIdx.x;
  const float* xr = x + (long)row * kH;
  float4 v = *(const float4*)(xr + tid * 4);
  float s = v.x + v.y + v.z + v.w;
  float s2 = v.x * v.x + v.y * v.y + v.z * v.z + v.w * v.w;
  __shared__ float red[8];
  for (int o = 32; o; o >>= 1) { s += __shfl_down(s, o); s2 += __shfl_down(s2, o); }
  int wv = tid >> 6, lane = tid & 63;
  if (lane == 0) { red[wv] = s; red[4 + wv] = s2; }
  __syncthreads();
  if (tid == 0) {
    red[0] = red[0] + red[1] + red[2] + red[3];
    red[4] = red[4] + red[5] + red[6] + red[7];
  }
  __syncthreads();
  float mean = red[0] * (1.0f / kH);
  float var = red[4] * (1.0f / kH) - mean * mean;
  float rs = rsqrtf(var + 1e-6f);
  float4 gv = *(const float4*)(g + tid * 4);
  float4 bv = *(const float4*)(b + tid * 4);
  float y0 = (v.x - mean) * rs * gv.x + bv.x;
  float y1 = (v.y - mean) * rs * gv.y + bv.y;
  float y2 = (v.z - mean) * rs * gv.z + bv.z;
  float y3 = (v.w - mean) * rs * gv.w + bv.w;
  long base = (long)row * kH + tid * 4;
  if (oh) {
    union { f16 h[4]; uint2 u; } o;
    o.h[0] = (f16)y0; o.h[1] = (f16)y1; o.h[2] = (f16)y2; o.h[3] = (f16)y3;
    *(uint2*)(oh + base) = o.u;
  }
  if (of) { float4 o4 = {y0, y1, y2, y3}; *(float4*)(of + base) = o4; }
}

__global__ void zero_kernel(int* __restrict__ p, int n) {
  int i = blockIdx.x * blockDim.x + threadIdx.x;
  if (i < n) p[i] = 0;
}

// ---------------- router: fp32 logits, first-index argmax, bucket tokens ----
__global__ __launch_bounds__(64) void router_kernel(const float* __restrict__ ca,
                                                    const float* __restrict__ gw,
                                                    const float* __restrict__ gb,
                                                    int* __restrict__ cursors,
                                                    int* __restrict__ list,
                                                    int* __restrict__ eid) {
  int t = blockIdx.x;
  int lane = threadIdx.x;
  const float* x = ca + (long)t * kH;
  float acc[kE];
#pragma unroll
  for (int e = 0; e < kE; e++) acc[e] = 0.0f;
  for (int h = lane; h < kH; h += 64) {
    float xv = x[h];
    const float* gr = gw + (long)h * kE;
#pragma unroll
    for (int e = 0; e < kE; e++) acc[e] += xv * gr[e];
  }
#pragma unroll
  for (int e = 0; e < kE; e++)
    for (int o = 32; o; o >>= 1) acc[e] += __shfl_down(acc[e], o);
  if (lane == 0) {
    int best = 0;
    float bv = acc[0] + gb[0];
    for (int e = 1; e < kE; e++) {
      float v = acc[e] + gb[e];
      if (v > bv) { bv = v; best = e; }  // strict > == first-index argmax
    }
    int slot = atomicAdd(&cursors[best], 1);
    list[best * kTok + slot] = t;
    eid[t] = best;
  }
}

// ---------------- FFN2 reduce: out = sum(part[0..3]) + b2[eid] + lnca --------
__global__ __launch_bounds__(256) void ffn2_reduce(const float* __restrict__ part,
                                                   const float* __restrict__ lnca,
                                                   const float* __restrict__ b2,
                                                   const int* __restrict__ eid,
                                                   float* __restrict__ out) {
  int t = blockIdx.x;
  int i = threadIdx.x * 4;
  int e = eid[t];
  long idx = (long)t * kH + i;
  float4 p0 = *(const float4*)(part + idx);
  float4 p1 = *(const float4*)(part + (long)kTok * kH + idx);
  float4 p2 = *(const float4*)(part + 2L * kTok * kH + idx);
  float4 p3 = *(const float4*)(part + 3L * kTok * kH + idx);
  float4 r  = *(const float4*)(lnca + idx);
  float4 bb = *(const float4*)(b2 + (long)e * kH + i);
  float4 o = {p0.x + p1.x + p2.x + p3.x + r.x + bb.x,
              p0.y + p1.y + p2.y + p3.y + r.y + bb.y,
              p0.z + p1.z + p2.z + p3.z + r.z + bb.z,
              p0.w + p1.w + p2.w + p3.w + r.w + bb.w};
  *(float4*)(out + idx) = o;
}

// ---------------- fused flash attention ----------------
// K/V staged row-contiguous (8 lanes per 128B row), XOR-swizzled source+read.
__global__ __launch_bounds__(256) void flash_kernel(const f16* __restrict__ q,
                                                    const f16* __restrict__ k,
                                                    const f16* __restrict__ v_t,
                                                    const float* __restrict__ mask,
                                                    f16* __restrict__ ctx) {
  __shared__ f16 Ks[64 * 64];
  __shared__ f16 Vs[64 * 64];
  __shared__ f16 Ps[4][16][72];  // pitch 72 (144B) breaks write conflicts
  int qt = blockIdx.x;
  int bh = blockIdx.y;
  int b = bh >> 4;
  int ho = (bh & 15) * 64;
  int tid = threadIdx.x, lane = tid & 63, wave = tid >> 6;
  int quad = lane >> 4, lo = lane & 15;

  long qg = ((long)b * kSQ + qt * 64 + wave * 16 + lo) * kH + ho;
  half8 aq0 = *(const half8*)(q + qg + quad * 8);
  half8 aq1 = *(const half8*)(q + qg + 32 + quad * 8);

  // staging: chunk c = s*256+tid -> row = c>>3, octet = (c&7) ^ (row&7)  [swizzled source]
  int srow = tid >> 3;                       // 0..31 within group
  int soct = (tid & 7) ^ (srow & 7);         // swizzled k/sk octet
  const f16* ksrc[2];
  const f16* vsrc[2];
#pragma unroll
  for (int s = 0; s < 2; s++) {
    int r = s * 32 + srow;
    ksrc[s] = k + ((long)b * kSK + r) * kH + ho + soct * 8;       // row = key
    vsrc[s] = v_t + ((long)bh * 64 + r) * kSK + soct * 8;         // row = d
  }
  const float* maskp = mask + ((long)b * kSQ + qt * 64 + wave * 16 + quad * 4) * kSK;

  float m_s[4] = {-1e30f, -1e30f, -1e30f, -1e30f};
  float l_s[4] = {0.f, 0.f, 0.f, 0.f};
  f32x4 O[4] = {};

  for (int kt = 0; kt < kSK / 64; kt++) {
    int sk0 = kt * 64;
#pragma unroll
    for (int s = 0; s < 2; s++) g2l16(ksrc[s] + (long)sk0 * kH, &Ks[(s * 256 + tid) * 8]);
#pragma unroll
    for (int s = 0; s < 2; s++) g2l16(vsrc[s] + sk0, &Vs[(s * 256 + tid) * 8]);
    __syncthreads();
    f32x4 sf[4] = {};
#pragma unroll
    for (int nt = 0; nt < 4; nt++) {
      int key = nt * 16 + lo;
      half8 bk0 = *(const half8*)&Ks[key * 64 + (((0 * 4 + quad)) ^ (key & 7)) * 8];
      half8 bk1 = *(const half8*)&Ks[key * 64 + (((1 * 4 + quad)) ^ (key & 7)) * 8];
      sf[nt] = __builtin_amdgcn_mfma_f32_16x16x32_f16(aq0, bk0, sf[nt], 0, 0, 0);
      sf[nt] = __builtin_amdgcn_mfma_f32_16x16x32_f16(aq1, bk1, sf[nt], 0, 0, 0);
    }
#pragma unroll
    for (int r = 0; r < 4; r++)
#pragma unroll
      for (int nt = 0; nt < 4; nt++)
        sf[nt][r] += maskp[(long)r * kSK + sk0 + nt * 16 + lo];
#pragma unroll
    for (int r = 0; r < 4; r++) {
      float mx = fmaxf(fmaxf(sf[0][r], sf[1][r]), fmaxf(sf[2][r], sf[3][r]));
      mx = fmaxf(mx, __shfl_xor(mx, 1));
      mx = fmaxf(mx, __shfl_xor(mx, 2));
      mx = fmaxf(mx, __shfl_xor(mx, 4));
      mx = fmaxf(mx, __shfl_xor(mx, 8));
      float m_new = fmaxf(m_s[r], mx);
      float alpha = __expf(m_s[r] - m_new);
      m_s[r] = m_new;
      float p0 = __expf(sf[0][r] - m_new), p1 = __expf(sf[1][r] - m_new);
      float p2 = __expf(sf[2][r] - m_new), p3 = __expf(sf[3][r] - m_new);
      float rs = p0 + p1 + p2 + p3;
      rs += __shfl_xor(rs, 1);
      rs += __shfl_xor(rs, 2);
      rs += __shfl_xor(rs, 4);
      rs += __shfl_xor(rs, 8);
      l_s[r] = l_s[r] * alpha + rs;
#pragma unroll
      for (int nt = 0; nt < 4; nt++) O[nt][r] *= alpha;
      Ps[wave][quad * 4 + r][0 * 16 + lo] = (f16)p0;
      Ps[wave][quad * 4 + r][1 * 16 + lo] = (f16)p1;
      Ps[wave][quad * 4 + r][2 * 16 + lo] = (f16)p2;
      Ps[wave][quad * 4 + r][3 * 16 + lo] = (f16)p3;
    }
    half8 ap0 = *(const half8*)&Ps[wave][lo][quad * 8];
    half8 ap1 = *(const half8*)&Ps[wave][lo][32 + quad * 8];
#pragma unroll
    for (int nt = 0; nt < 4; nt++) {
      int d = nt * 16 + lo;
      half8 bv0 = *(const half8*)&Vs[d * 64 + (((0 * 4 + quad)) ^ (d & 7)) * 8];
      half8 bv1 = *(const half8*)&Vs[d * 64 + (((1 * 4 + quad)) ^ (d & 7)) * 8];
      O[nt] = __builtin_amdgcn_mfma_f32_16x16x32_f16(ap0, bv0, O[nt], 0, 0, 0);
      O[nt] = __builtin_amdgcn_mfma_f32_16x16x32_f16(ap1, bv1, O[nt], 0, 0, 0);
    }
    __syncthreads();
  }
#pragma unroll
  for (int r = 0; r < 4; r++) {
    float inv = 1.0f / l_s[r];
    long row = (long)b * kSQ + qt * 64 + wave * 16 + quad * 4 + r;
#pragma unroll
    for (int nt = 0; nt < 4; nt++)
      ctx[row * kH + ho + nt * 16 + lo] = (f16)(O[nt][r] * inv);
  }
}

// ---------------- tiled fp16 MFMA GEMM, BK=64, SINGLE-buffer g2l staging -----
// C[M,N] = epilogue(A[M,K] @ B[N,K]^T); B is [N][K] k-contiguous.
// m97 structure: stage -> sync -> compute -> sync; 32KB LDS at 128x128 keeps
// 4 blocks/CU resident (the TLP hides the barrier drain; dbuf never did).
// Row-contiguous staging (8 lanes per 128B row), XOR-swizzled source + reads.
struct GemmP {
  const f16* A; long a_row, a_z1, a_z2;
  const f16* Bm; long b_nstr, b_z1, b_z2;
  float* Cf; f16* Ch; long c_row, c_z1, c_z2, c_split; int c_tr;
  const float* bias; long bias_z;
  const float* res; long res_row, res_z1, res_z2;
  float alpha; int gelu; int ksplit;
  int M, N, K, zdiv;
  const int* glist; const int* cnt;  // expert-gather mode: z = expert
};

template <int BM, int BN>
__device__ __forceinline__ void gemm_body(const GemmP& p, int bx, int by, int bz,
                                          f16* A0, f16* B0) {
  constexpr int FM = BM / 32, FN = BN / 32;
  int z = bz;
  int kb = 0, kEnd = p.K, ks = 0;
  if (p.ksplit > 1) {
    int kc = p.K / p.ksplit;
    ks = z % p.ksplit;
    kb = ks * kc;
    kEnd = kb + kc;
    z /= p.ksplit;
  }
  long aoff = 0, boff = 0, coff = 0, roff = 0, biasoff = 0;
  const int* gl = nullptr;
  int Meff = p.M;
  if (p.glist) {
    Meff = p.cnt[z];
    gl = p.glist + (long)z * kTok;
    boff = (long)z * p.b_z2;
    biasoff = (long)z * p.bias_z;
  } else {
    int z1 = z / p.zdiv, z2 = z % p.zdiv;
    aoff = (long)z1 * p.a_z1 + (long)z2 * p.a_z2;
    boff = (long)z1 * p.b_z1 + (long)z2 * p.b_z2;
    coff = (long)z1 * p.c_z1 + (long)z2 * p.c_z2;
    roff = (long)z1 * p.res_z1 + (long)z2 * p.res_z2;
  }
  coff += (long)ks * p.c_split;
  int m0 = by * BM;
  if (m0 >= Meff) return;
  int n0 = bx * BN;
  int tid = threadIdx.x, lane = tid & 63, wave = tid >> 6;
  int wm = (wave & 1) * (BM / 2), wn = (wave >> 1) * (BN / 2);
  int q = lane >> 4, lo = lane & 15;

  // row-contiguous staging: chunk c = s*256+tid -> row = s*32 + (tid>>3),
  // source k-octet = (tid&7) ^ (row&7); LDS dest linear -> [row][slot].
  int srow = tid >> 3;
  int soct = (tid & 7) ^ (srow & 7);
  const f16* asrc[BM / 32];
  const f16* bsrc[BN / 32];
#pragma unroll
  for (int s = 0; s < BM / 32; s++) {
    int row = m0 + s * 32 + srow;
    if (gl) row = gl[row < Meff ? row : Meff - 1];  // clamp: garbage rows never stored
    asrc[s] = p.A + aoff + (long)row * p.a_row + soct * 8;
  }
#pragma unroll
  for (int s = 0; s < BN / 32; s++)
    bsrc[s] = p.Bm + boff + (long)(n0 + s * 32 + srow) * p.b_nstr + soct * 8;

  f32x4 acc[FM][FN] = {};

  auto stage = [&](f16* Ad, f16* Bd, int k0) {
#pragma unroll
    for (int s = 0; s < BM / 32; s++) g2l16(asrc[s] + k0, &Ad[(s * 256 + tid) * 8]);
#pragma unroll
    for (int s = 0; s < BN / 32; s++) g2l16(bsrc[s] + k0, &Bd[(s * 256 + tid) * 8]);
  };
  auto compute = [&](const f16* As, const f16* Bs) {
    half8 af[2][FM], bf[2][FN];
#pragma unroll
    for (int kk = 0; kk < 2; kk++) {
#pragma unroll
      for (int i = 0; i < FM; i++) {
        int r = wm + i * 16 + lo;
        af[kk][i] = *(const half8*)&As[r * 64 + ((kk * 4 + q) ^ (r & 7)) * 8];
      }
#pragma unroll
      for (int j = 0; j < FN; j++) {
        int n = wn + j * 16 + lo;
        bf[kk][j] = *(const half8*)&Bs[n * 64 + ((kk * 4 + q) ^ (n & 7)) * 8];
      }
    }
#pragma unroll
    for (int kk = 0; kk < 2; kk++)
#pragma unroll
      for (int i = 0; i < FM; i++)
#pragma unroll
        for (int j = 0; j < FN; j++)
          acc[i][j] = __builtin_amdgcn_mfma_f32_16x16x32_f16(af[kk][i], bf[kk][j], acc[i][j], 0, 0, 0);
  };

  // single-buffer m97 loop: two barriers per K-step; TLP (4 blocks/CU) hides drain.
  for (int k0 = kb; k0 < kEnd; k0 += 64) {
    stage(A0, B0, k0);
    __syncthreads();
    compute(A0, B0);
    __syncthreads();
  }

#pragma unroll
  for (int i = 0; i < FM; i++) {
#pragma unroll
    for (int j = 0; j < FN; j++) {
      int col = n0 + wn + j * 16 + lo;
      if (p.c_tr) {  // transposed f16 store: 4 consecutive rows -> one 8B store
        int row0 = m0 + wm + i * 16 + q * 4;
        union { f16 h[4]; uint2 u; } o;
#pragma unroll
        for (int r = 0; r < 4; r++) {
          float v = acc[i][j][r];
          if (p.bias) v += p.bias[biasoff + col];
          v *= p.alpha;
          o.h[r] = (f16)v;
        }
        *(uint2*)&p.Ch[coff + (long)col * p.c_row + row0] = o.u;
      } else {
#pragma unroll
        for (int r = 0; r < 4; r++) {
          int row = m0 + wm + i * 16 + q * 4 + r;
          if (row < Meff) {
            long rr = gl ? (long)gl[row] : (long)row;
            float v = acc[i][j][r];
            if (p.bias) v += p.bias[biasoff + col];
            v *= p.alpha;
            if (p.res) v += p.res[roff + rr * p.res_row + col];
            if (p.gelu) v = 0.5f * v * (1.0f + erff(v * 0.70710678118654752f));
            long ci = coff + rr * p.c_row + col;
            if (p.Cf) p.Cf[ci] = v;
            else p.Ch[ci] = (f16)v;
          }
        }
      }
    }
  }
}

template <int BM, int BN>
__global__ __launch_bounds__(256) void gemm_t(GemmP p) {
  __shared__ f16 A0[BM * 64], B0[BN * 64];
  gemm_body<BM, BN>(p, blockIdx.x, blockIdx.y, blockIdx.z, A0, B0);
}

// fused Q/K/V projections: one flat grid, block ranges per sub-GEMM (128x128 tiles)
struct Multi3P {
  GemmP g0, g1, g2;
  int n0, n1;
  int gx0, gy0, gx1, gy1, gx2, gy2;
};

__global__ __launch_bounds__(256) void gemm_qkv(Multi3P mp) {
  __shared__ f16 A0[128 * 64], B0[128 * 64];
  int fb = blockIdx.x;
  if (fb < mp.n0) {
    gemm_body<128, 128>(mp.g0, fb % mp.gx0, (fb / mp.gx0) % mp.gy0, fb / (mp.gx0 * mp.gy0),
                        A0, B0);
    return;
  }
  fb -= mp.n0;
  if (fb < mp.n1) {
    gemm_body<128, 128>(mp.g1, fb % mp.gx1, (fb / mp.gx1) % mp.gy1, fb / (mp.gx1 * mp.gy1),
                        A0, B0);
    return;
  }
  fb -= mp.n1;
  gemm_body<128, 128>(mp.g2, fb % mp.gx2, (fb / mp.gx2) % mp.gy2, fb / (mp.gx2 * mp.gy2),
                      A0, B0);
}

extern "C" void kernel_launch(void* const* d_in, const int* in_sizes, int n_in,
                              void* d_out, int out_size, void* d_ws, size_t ws_size,
                              hipStream_t stream) {
  const float* concated = (const float*)d_in[0];
  const float* gen      = (const float*)d_in[1];
  const float* mask     = (const float*)d_in[2];
  const float* ln_g     = (const float*)d_in[3];
  const float* ln_b     = (const float*)d_in[4];
  const float* wq = (const float*)d_in[5];  const float* bq = (const float*)d_in[6];
  const float* wk = (const float*)d_in[7];  const float* bk = (const float*)d_in[8];
  const float* wv = (const float*)d_in[9];  const float* bv = (const float*)d_in[10];
  const float* wo = (const float*)d_in[11]; const float* bo = (const float*)d_in[12];
  const float* gw = (const float*)d_in[13]; const float* gb = (const float*)d_in[14];
  const float* w1 = (const float*)d_in[15]; const float* b1 = (const float*)d_in[16];
  const float* w2 = (const float*)d_in[17]; const float* b2 = (const float*)d_in[18];
  float* out = (float*)d_out;

  size_t off = 0;
  auto alloc = [&](size_t bytes) -> void* {
    void* p = (char*)d_ws + off;
    off += (bytes + 255) & ~(size_t)255;
    return p;
  };
  f16* wq_t  = (f16*)alloc((size_t)kH * kH * 2);       // [N][K]
  f16* wk_t  = (f16*)alloc((size_t)kH * kH * 2);
  f16* wv_t  = (f16*)alloc((size_t)kH * kH * 2);
  f16* wo_t  = (f16*)alloc((size_t)kH * kH * 2);
  f16* w1_t  = (f16*)alloc((size_t)kE * kH * kDFF * 2);  // [E][DFF][H]
  f16* w2_t  = (f16*)alloc((size_t)kE * kDFF * kH * 2);  // [E][H][DFF]
  f16* lnc_h = (f16*)alloc((size_t)kB * kSK * kH * 2);
  f16* lng_h = (f16*)alloc((size_t)kTok * kH * 2);
  f16* q_h   = (f16*)alloc((size_t)kTok * kH * 2);
  f16* k_h   = (f16*)alloc((size_t)kB * kSK * kH * 2);
  f16* v_t   = (f16*)alloc((size_t)kB * kSK * kH * 2);   // [b][h][d][sk]
  f16* ctx_h = (f16*)alloc((size_t)kTok * kH * 2);
  float* ca_f   = (float*)alloc((size_t)kTok * kH * 4);
  float* lnca_f = (float*)alloc((size_t)kTok * kH * 4);
  f16* lnca_h   = (f16*)alloc((size_t)kTok * kH * 2);
  f16* h1_h     = (f16*)alloc((size_t)kTok * kDFF * 2);
  float* part_f = (float*)alloc((size_t)4 * kTok * kH * 4);
  int* cnt_d    = (int*)alloc(kE * 4);
  int* list_d   = (int*)alloc((size_t)kE * kTok * 4);
  int* eid_d    = (int*)alloc((size_t)kTok * 4);

  // ---- weight transpose-convert fp32 [K][N] -> fp16 [N][K] ----
  tr_f2h<<<dim3(32, 32, 1), 256, 0, stream>>>(wq, wq_t, kH, kH);
  tr_f2h<<<dim3(32, 32, 1), 256, 0, stream>>>(wk, wk_t, kH, kH);
  tr_f2h<<<dim3(32, 32, 1), 256, 0, stream>>>(wv, wv_t, kH, kH);
  tr_f2h<<<dim3(32, 32, 1), 256, 0, stream>>>(wo, wo_t, kH, kH);
  tr_f2h<<<dim3(kDFF / 32, kH / 32, kE), 256, 0, stream>>>(w1, w1_t, kH, kDFF);
  tr_f2h<<<dim3(kH / 32, kDFF / 32, kE), 256, 0, stream>>>(w2, w2_t, kDFF, kH);

  // ---- LayerNorms of inputs ----
  ln_kernel<<<kB * kSK, 256, 0, stream>>>(concated, ln_g, ln_b, lnc_h, nullptr, kB * kSK);
  ln_kernel<<<kTok, 256, 0, stream>>>(gen, ln_g, ln_b, lng_h, nullptr, kTok);

  // ---- fused Q/K/V projections (one launch, 640 blocks at 128x128) ----
  {
    Multi3P mp{};
    GemmP& pq = mp.g0;
    pq.A = lng_h; pq.a_row = kH; pq.Bm = wq_t; pq.b_nstr = kH;
    pq.Ch = q_h; pq.c_row = kH; pq.bias = bq; pq.alpha = 0.125f;
    pq.M = kTok; pq.N = kH; pq.K = kH; pq.zdiv = 1;
    GemmP& pk = mp.g1;
    pk.A = lnc_h; pk.a_row = kH; pk.Bm = wk_t; pk.b_nstr = kH;
    pk.Ch = k_h; pk.c_row = kH; pk.bias = bk; pk.alpha = 1.0f;
    pk.M = kB * kSK; pk.N = kH; pk.K = kH; pk.zdiv = 1;
    GemmP& pv = mp.g2;
    pv.A = lnc_h; pv.a_row = kH; pv.a_z1 = (long)kSK * kH;
    pv.Bm = wv_t; pv.b_nstr = kH;
    pv.Ch = v_t; pv.c_row = kSK; pv.c_z1 = (long)kH * kSK; pv.c_tr = 1;
    pv.bias = bv; pv.alpha = 1.0f;
    pv.M = kSK; pv.N = kH; pv.K = kH; pv.zdiv = 1;
    mp.gx0 = kH / 128; mp.gy0 = kTok / 128;        mp.n0 = mp.gx0 * mp.gy0;       // 128
    mp.gx1 = kH / 128; mp.gy1 = (kB * kSK) / 128;  mp.n1 = mp.gx1 * mp.gy1;       // 256
    mp.gx2 = kH / 128; mp.gy2 = kSK / 128;                                         // x8, z=4
    int ntot = mp.n0 + mp.n1 + mp.gx2 * mp.gy2 * kB;                               // 640
    gemm_qkv<<<dim3(ntot), 256, 0, stream>>>(mp);
  }
  // ---- fused flash attention -> ctx_h ----
  flash_kernel<<<dim3(kSQ / 64, kB * kHeads), 256, 0, stream>>>(q_h, k_h, v_t, mask, ctx_h);
  // ---- ca_out = ctx @ wo^T + bo + gen (fp32 out) ----
  {
    GemmP p{}; p.A = ctx_h; p.a_row = kH;
    p.Bm = wo_t; p.b_nstr = kH;
    p.Cf = ca_f; p.c_row = kH; p.bias = bo;
    p.res = gen; p.res_row = kH;
    p.alpha = 1.0f; p.M = kTok; p.N = kH; p.K = kH; p.zdiv = 1;
    gemm_t<64, 64><<<dim3(kH / 64, kTok / 64, 1), 256, 0, stream>>>(p);
  }
  // ---- ln_ca (fp32 + fp16) ----
  ln_kernel<<<kTok, 256, 0, stream>>>(ca_f, ln_g, ln_b, lnca_h, lnca_f, kTok);
  // ---- router + expert bucketing ----
  zero_kernel<<<1, 64, 0, stream>>>(cnt_d, kE);
  router_kernel<<<kTok, 64, 0, stream>>>(ca_f, gw, gb, cnt_d, list_d, eid_d);
  // ---- FFN1: h1 = gelu(ln_ca @ w1[e] + b1[e]) ; 128x128 tile ----
  {
    GemmP p{}; p.A = lnca_h; p.a_row = kH;
    p.Bm = w1_t; p.b_nstr = kH; p.b_z2 = (long)kH * kDFF;
    p.Ch = h1_h; p.c_row = kDFF; p.bias = b1; p.bias_z = kDFF;
    p.alpha = 1.0f; p.gelu = 1; p.M = kTok; p.N = kDFF; p.K = kH; p.zdiv = 1;
    p.glist = list_d; p.cnt = cnt_d;
    gemm_t<128, 128><<<dim3(kDFF / 128, kTok / 128, kE), 256, 0, stream>>>(p);
  }
  // ---- FFN2: part[s] = h1 @ w2[e] (split-K x4, fp32 partials, no atomics) ----
  {
    GemmP p{}; p.A = h1_h; p.a_row = kDFF;
    p.Bm = w2_t; p.b_nstr = kDFF; p.b_z2 = (long)kDFF * kH;
    p.Cf = part_f; p.c_row = kH; p.c_split = (long)kTok * kH;
    p.alpha = 1.0f; p.ksplit = 4;
    p.M = kTok; p.N = kH; p.K = kDFF; p.zdiv = 1;
    p.glist = list_d; p.cnt = cnt_d;
    gemm_t<128, 128><<<dim3(kH / 128, kTok / 128, kE * 4), 256, 0, stream>>>(p);
  }
  // ---- reduce: out = sum(part) + b2[eid] + lnca ----
  ffn2_reduce<<<kTok, 256, 0, stream>>>(part_f, lnca_f, b2, eid_d, out);
}

// Round 9
// 689.982 us; speedup vs baseline: 1.0563x; 1.0420x over previous
//
#include <hip/hip_runtime.h>
#include <stdint.h>
#include <stddef.h>

typedef _Float16 f16;
typedef _Float16 half8 __attribute__((ext_vector_type(8)));
typedef float f32x4 __attribute__((ext_vector_type(4)));

constexpr int kB = 4, kSQ = 512, kSK = 1024, kH = 1024, kHeads = 16, kE = 8, kDFF = 4096;
constexpr int kTok = kB * kSQ;  // 2048 gen tokens

// async global->LDS, 16B per lane; LDS dest must be wave-uniform base + lane*16
__device__ __forceinline__ void g2l16(const f16* g, f16* l) {
  __builtin_amdgcn_global_load_lds((const __attribute__((address_space(1))) uint32_t*)g,
                                   (__attribute__((address_space(3))) uint32_t*)l, 16, 0, 0);
}

// bijective XCD chunk swizzle (T1): physical round-robin -> contiguous logical
// chunk per XCD. Requires nwg % 8 == 0 (all our grids are).
__device__ __forceinline__ int xcd_swz(int phys, int nwg) {
  return (phys & 7) * (nwg >> 3) + (phys >> 3);
}

// ---------------- transpose + fp32->fp16: dst[C][R] = (f16)src[R][C], batched over z
__global__ __launch_bounds__(256) void tr_f2h(const float* __restrict__ src,
                                              f16* __restrict__ dst, int R, int C) {
  __shared__ float t[32][33];
  long zo = (long)blockIdx.z * R * C;
  int r0 = blockIdx.y * 32, c0 = blockIdx.x * 32;
  int tr = threadIdx.x >> 3, tc = (threadIdx.x & 7) << 2;
  float4 v = *(const float4*)(src + zo + (long)(r0 + tr) * C + c0 + tc);
  t[tr][tc] = v.x; t[tr][tc + 1] = v.y; t[tr][tc + 2] = v.z; t[tr][tc + 3] = v.w;
  __syncthreads();
  union { f16 h[4]; uint2 u; } o;
  o.h[0] = (f16)t[tc + 0][tr]; o.h[1] = (f16)t[tc + 1][tr];
  o.h[2] = (f16)t[tc + 2][tr]; o.h[3] = (f16)t[tc + 3][tr];
  *(uint2*)(dst + zo + (long)(c0 + tr) * R + r0 + tc) = o.u;
}

// four 1024x1024 weight transposes in one launch (z selects matrix)
struct Tr4P { const float* s0; const float* s1; const float* s2; const float* s3;
              f16* d0; f16* d1; f16* d2; f16* d3; };
__global__ __launch_bounds__(256) void tr_f2h4(Tr4P tp) {
  __shared__ float t[32][33];
  int z = blockIdx.z;
  const float* src = z == 0 ? tp.s0 : z == 1 ? tp.s1 : z == 2 ? tp.s2 : tp.s3;
  f16* dst = z == 0 ? tp.d0 : z == 1 ? tp.d1 : z == 2 ? tp.d2 : tp.d3;
  int r0 = blockIdx.y * 32, c0 = blockIdx.x * 32;
  int tr = threadIdx.x >> 3, tc = (threadIdx.x & 7) << 2;
  float4 v = *(const float4*)(src + (long)(r0 + tr) * kH + c0 + tc);
  t[tr][tc] = v.x; t[tr][tc + 1] = v.y; t[tr][tc + 2] = v.z; t[tr][tc + 3] = v.w;
  __syncthreads();
  union { f16 h[4]; uint2 u; } o;
  o.h[0] = (f16)t[tc + 0][tr]; o.h[1] = (f16)t[tc + 1][tr];
  o.h[2] = (f16)t[tc + 2][tr]; o.h[3] = (f16)t[tc + 3][tr];
  *(uint2*)(dst + (long)(c0 + tr) * kH + r0 + tc) = o.u;
}

// ---------------- LayerNorm over H=1024, one block (256 thr) per row --------
__global__ __launch_bounds__(256) void ln_kernel(const float* __restrict__ x,
                                                 const float* __restrict__ g,
                                                 const float* __restrict__ b,
                                                 f16* __restrict__ oh, float* __restrict__ of,
                                                 int rows) {
  int row = blockIdx.x;
  if (row >= rows) return;
  int tid = threadIdx.x;
  const float* xr = x + (long)row * kH;
  float4 v = *(const float4*)(xr + tid * 4);
  float s = v.x + v.y + v.z + v.w;
  float s2 = v.x * v.x + v.y * v.y + v.z * v.z + v.w * v.w;
  __shared__ float red[8];
  for (int o = 32; o; o >>= 1) { s += __shfl_down(s, o); s2 += __shfl_down(s2, o); }
  int wv = tid >> 6, lane = tid & 63;
  if (lane == 0) { red[wv] = s; red[4 + wv] = s2; }
  __syncthreads();
  if (tid == 0) {
    red[0] = red[0] + red[1] + red[2] + red[3];
    red[4] = red[4] + red[5] + red[6] + red[7];
  }
  __syncthreads();
  float mean = red[0] * (1.0f / kH);
  float var = red[4] * (1.0f / kH) - mean * mean;
  float rs = rsqrtf(var + 1e-6f);
  float4 gv = *(const float4*)(g + tid * 4);
  float4 bv = *(const float4*)(b + tid * 4);
  float y0 = (v.x - mean) * rs * gv.x + bv.x;
  float y1 = (v.y - mean) * rs * gv.y + bv.y;
  float y2 = (v.z - mean) * rs * gv.z + bv.z;
  float y3 = (v.w - mean) * rs * gv.w + bv.w;
  long base = (long)row * kH + tid * 4;
  if (oh) {
    union { f16 h[4]; uint2 u; } o;
    o.h[0] = (f16)y0; o.h[1] = (f16)y1; o.h[2] = (f16)y2; o.h[3] = (f16)y3;
    *(uint2*)(oh + base) = o.u;
  }
  if (of) { float4 o4 = {y0, y1, y2, y3}; *(float4*)(of + base) = o4; }
}

__global__ void zero_kernel(int* __restrict__ p, int n) {
  int i = blockIdx.x * blockDim.x + threadIdx.x;
  if (i < n) p[i] = 0;
}

// ---------------- router: fp32 logits, first-index argmax, bucket tokens ----
__global__ __launch_bounds__(64) void router_kernel(const float* __restrict__ ca,
                                                    const float* __restrict__ gw,
                                                    const float* __restrict__ gb,
                                                    int* __restrict__ cursors,
                                                    int* __restrict__ list,
                                                    int* __restrict__ eid) {
  int t = blockIdx.x;
  int lane = threadIdx.x;
  const float* x = ca + (long)t * kH;
  float acc[kE];
#pragma unroll
  for (int e = 0; e < kE; e++) acc[e] = 0.0f;
  for (int h = lane; h < kH; h += 64) {
    float xv = x[h];
    const float* gr = gw + (long)h * kE;
#pragma unroll
    for (int e = 0; e < kE; e++) acc[e] += xv * gr[e];
  }
#pragma unroll
  for (int e = 0; e < kE; e++)
    for (int o = 32; o; o >>= 1) acc[e] += __shfl_down(acc[e], o);
  if (lane == 0) {
    int best = 0;
    float bv = acc[0] + gb[0];
    for (int e = 1; e < kE; e++) {
      float v = acc[e] + gb[e];
      if (v > bv) { bv = v; best = e; }  // strict > == first-index argmax
    }
    int slot = atomicAdd(&cursors[best], 1);
    list[best * kTok + slot] = t;
    eid[t] = best;
  }
}

// ---------------- FFN2 reduce: out = sum(part[0..3]) + b2[eid] + lnca --------
__global__ __launch_bounds__(256) void ffn2_reduce(const float* __restrict__ part,
                                                   const float* __restrict__ lnca,
                                                   const float* __restrict__ b2,
                                                   const int* __restrict__ eid,
                                                   float* __restrict__ out) {
  int t = blockIdx.x;
  int i = threadIdx.x * 4;
  int e = eid[t];
  long idx = (long)t * kH + i;
  float4 p0 = *(const float4*)(part + idx);
  float4 p1 = *(const float4*)(part + (long)kTok * kH + idx);
  float4 p2 = *(const float4*)(part + 2L * kTok * kH + idx);
  float4 p3 = *(const float4*)(part + 3L * kTok * kH + idx);
  float4 r  = *(const float4*)(lnca + idx);
  float4 bb = *(const float4*)(b2 + (long)e * kH + i);
  float4 o = {p0.x + p1.x + p2.x + p3.x + r.x + bb.x,
              p0.y + p1.y + p2.y + p3.y + r.y + bb.y,
              p0.z + p1.z + p2.z + p3.z + r.z + bb.z,
              p0.w + p1.w + p2.w + p3.w + r.w + bb.w};
  *(float4*)(out + idx) = o;
}

// ---------------- fused flash attention ----------------
// K/V staged row-contiguous (8 lanes per 128B row), XOR-swizzled source+read.
// 1D grid with XCD swizzle: same-bh blocks (sharing K/V) group on one XCD.
__global__ __launch_bounds__(256) void flash_kernel(const f16* __restrict__ q,
                                                    const f16* __restrict__ k,
                                                    const f16* __restrict__ v_t,
                                                    const float* __restrict__ mask,
                                                    f16* __restrict__ ctx) {
  __shared__ f16 Ks[64 * 64];
  __shared__ f16 Vs[64 * 64];
  __shared__ f16 Ps[4][16][72];  // pitch 72 (144B) breaks write conflicts
  int l = xcd_swz(blockIdx.x, gridDim.x);
  int qt = l & 7;          // kSQ/64 = 8 q-tiles, fastest
  int bh = l >> 3;
  int b = bh >> 4;
  int ho = (bh & 15) * 64;
  int tid = threadIdx.x, lane = tid & 63, wave = tid >> 6;
  int quad = lane >> 4, lo = lane & 15;

  long qg = ((long)b * kSQ + qt * 64 + wave * 16 + lo) * kH + ho;
  half8 aq0 = *(const half8*)(q + qg + quad * 8);
  half8 aq1 = *(const half8*)(q + qg + 32 + quad * 8);

  // staging: chunk c = s*256+tid -> row = c>>3, octet = (c&7) ^ (row&7)  [swizzled source]
  int srow = tid >> 3;                       // 0..31 within group
  int soct = (tid & 7) ^ (srow & 7);         // swizzled k/sk octet
  const f16* ksrc[2];
  const f16* vsrc[2];
#pragma unroll
  for (int s = 0; s < 2; s++) {
    int r = s * 32 + srow;
    ksrc[s] = k + ((long)b * kSK + r) * kH + ho + soct * 8;       // row = key
    vsrc[s] = v_t + ((long)bh * 64 + r) * kSK + soct * 8;         // row = d
  }
  const float* maskp = mask + ((long)b * kSQ + qt * 64 + wave * 16 + quad * 4) * kSK;

  float m_s[4] = {-1e30f, -1e30f, -1e30f, -1e30f};
  float l_s[4] = {0.f, 0.f, 0.f, 0.f};
  f32x4 O[4] = {};

  for (int kt = 0; kt < kSK / 64; kt++) {
    int sk0 = kt * 64;
#pragma unroll
    for (int s = 0; s < 2; s++) g2l16(ksrc[s] + (long)sk0 * kH, &Ks[(s * 256 + tid) * 8]);
#pragma unroll
    for (int s = 0; s < 2; s++) g2l16(vsrc[s] + sk0, &Vs[(s * 256 + tid) * 8]);
    __syncthreads();
    f32x4 sf[4] = {};
#pragma unroll
    for (int nt = 0; nt < 4; nt++) {
      int key = nt * 16 + lo;
      half8 bk0 = *(const half8*)&Ks[key * 64 + (((0 * 4 + quad)) ^ (key & 7)) * 8];
      half8 bk1 = *(const half8*)&Ks[key * 64 + (((1 * 4 + quad)) ^ (key & 7)) * 8];
      sf[nt] = __builtin_amdgcn_mfma_f32_16x16x32_f16(aq0, bk0, sf[nt], 0, 0, 0);
      sf[nt] = __builtin_amdgcn_mfma_f32_16x16x32_f16(aq1, bk1, sf[nt], 0, 0, 0);
    }
#pragma unroll
    for (int r = 0; r < 4; r++)
#pragma unroll
      for (int nt = 0; nt < 4; nt++)
        sf[nt][r] += maskp[(long)r * kSK + sk0 + nt * 16 + lo];
#pragma unroll
    for (int r = 0; r < 4; r++) {
      float mx = fmaxf(fmaxf(sf[0][r], sf[1][r]), fmaxf(sf[2][r], sf[3][r]));
      mx = fmaxf(mx, __shfl_xor(mx, 1));
      mx = fmaxf(mx, __shfl_xor(mx, 2));
      mx = fmaxf(mx, __shfl_xor(mx, 4));
      mx = fmaxf(mx, __shfl_xor(mx, 8));
      float m_new = fmaxf(m_s[r], mx);
      float alpha = __expf(m_s[r] - m_new);
      m_s[r] = m_new;
      float p0 = __expf(sf[0][r] - m_new), p1 = __expf(sf[1][r] - m_new);
      float p2 = __expf(sf[2][r] - m_new), p3 = __expf(sf[3][r] - m_new);
      float rs = p0 + p1 + p2 + p3;
      rs += __shfl_xor(rs, 1);
      rs += __shfl_xor(rs, 2);
      rs += __shfl_xor(rs, 4);
      rs += __shfl_xor(rs, 8);
      l_s[r] = l_s[r] * alpha + rs;
#pragma unroll
      for (int nt = 0; nt < 4; nt++) O[nt][r] *= alpha;
      Ps[wave][quad * 4 + r][0 * 16 + lo] = (f16)p0;
      Ps[wave][quad * 4 + r][1 * 16 + lo] = (f16)p1;
      Ps[wave][quad * 4 + r][2 * 16 + lo] = (f16)p2;
      Ps[wave][quad * 4 + r][3 * 16 + lo] = (f16)p3;
    }
    half8 ap0 = *(const half8*)&Ps[wave][lo][quad * 8];
    half8 ap1 = *(const half8*)&Ps[wave][lo][32 + quad * 8];
#pragma unroll
    for (int nt = 0; nt < 4; nt++) {
      int d = nt * 16 + lo;
      half8 bv0 = *(const half8*)&Vs[d * 64 + (((0 * 4 + quad)) ^ (d & 7)) * 8];
      half8 bv1 = *(const half8*)&Vs[d * 64 + (((1 * 4 + quad)) ^ (d & 7)) * 8];
      O[nt] = __builtin_amdgcn_mfma_f32_16x16x32_f16(ap0, bv0, O[nt], 0, 0, 0);
      O[nt] = __builtin_amdgcn_mfma_f32_16x16x32_f16(ap1, bv1, O[nt], 0, 0, 0);
    }
    __syncthreads();
  }
#pragma unroll
  for (int r = 0; r < 4; r++) {
    float inv = 1.0f / l_s[r];
    long row = (long)b * kSQ + qt * 64 + wave * 16 + quad * 4 + r;
#pragma unroll
    for (int nt = 0; nt < 4; nt++)
      ctx[row * kH + ho + nt * 16 + lo] = (f16)(O[nt][r] * inv);
  }
}

// ---------------- tiled fp16 MFMA GEMM, BK=64, double-buffered g2l staging ---
// C[M,N] = epilogue(A[M,K] @ B[N,K]^T); B is [N][K] k-contiguous.
// Row-contiguous staging (8 lanes per 128B row), XOR-swizzled source + reads.
// 2-phase dbuf (round-6 proven best); 1D grid + XCD chunk swizzle (T1).
struct GemmP {
  const f16* A; long a_row, a_z1, a_z2;
  const f16* Bm; long b_nstr, b_z1, b_z2;
  float* Cf; f16* Ch; long c_row, c_z1, c_z2, c_split; int c_tr;
  const float* bias; long bias_z;
  const float* res; long res_row, res_z1, res_z2;
  float alpha; int gelu; int ksplit;
  int M, N, K, zdiv;
  int gx, gy;  // logical grid dims (z = rest)
  const int* glist; const int* cnt;  // expert-gather mode: z = expert
};

template <int BM, int BN>
__device__ __forceinline__ void gemm_body(const GemmP& p, int bx, int by, int bz,
                                          f16* A0, f16* A1, f16* B0, f16* B1) {
  constexpr int FM = BM / 32, FN = BN / 32;
  int z = bz;
  int kb = 0, kEnd = p.K, ks = 0;
  if (p.ksplit > 1) {
    int kc = p.K / p.ksplit;
    ks = z % p.ksplit;
    kb = ks * kc;
    kEnd = kb + kc;
    z /= p.ksplit;
  }
  long aoff = 0, boff = 0, coff = 0, roff = 0, biasoff = 0;
  const int* gl = nullptr;
  int Meff = p.M;
  if (p.glist) {
    Meff = p.cnt[z];
    gl = p.glist + (long)z * kTok;
    boff = (long)z * p.b_z2;
    biasoff = (long)z * p.bias_z;
  } else {
    int z1 = z / p.zdiv, z2 = z % p.zdiv;
    aoff = (long)z1 * p.a_z1 + (long)z2 * p.a_z2;
    boff = (long)z1 * p.b_z1 + (long)z2 * p.b_z2;
    coff = (long)z1 * p.c_z1 + (long)z2 * p.c_z2;
    roff = (long)z1 * p.res_z1 + (long)z2 * p.res_z2;
  }
  coff += (long)ks * p.c_split;
  int m0 = by * BM;
  if (m0 >= Meff) return;
  int n0 = bx * BN;
  int tid = threadIdx.x, lane = tid & 63, wave = tid >> 6;
  int wm = (wave & 1) * (BM / 2), wn = (wave >> 1) * (BN / 2);
  int q = lane >> 4, lo = lane & 15;

  // row-contiguous staging: chunk c = s*256+tid -> row = s*32 + (tid>>3),
  // source k-octet = (tid&7) ^ (row&7); LDS dest linear -> [row][slot].
  int srow = tid >> 3;
  int soct = (tid & 7) ^ (srow & 7);
  const f16* asrc[BM / 32];
  const f16* bsrc[BN / 32];
#pragma unroll
  for (int s = 0; s < BM / 32; s++) {
    int row = m0 + s * 32 + srow;
    if (gl) row = gl[row < Meff ? row : Meff - 1];  // clamp: garbage rows never stored
    asrc[s] = p.A + aoff + (long)row * p.a_row + soct * 8;
  }
#pragma unroll
  for (int s = 0; s < BN / 32; s++)
    bsrc[s] = p.Bm + boff + (long)(n0 + s * 32 + srow) * p.b_nstr + soct * 8;

  f32x4 acc[FM][FN] = {};

  auto stage = [&](f16* Ad, f16* Bd, int k0) {
#pragma unroll
    for (int s = 0; s < BM / 32; s++) g2l16(asrc[s] + k0, &Ad[(s * 256 + tid) * 8]);
#pragma unroll
    for (int s = 0; s < BN / 32; s++) g2l16(bsrc[s] + k0, &Bd[(s * 256 + tid) * 8]);
  };
  auto compute = [&](const f16* As, const f16* Bs) {
    half8 af[2][FM], bf[2][FN];
#pragma unroll
    for (int kk = 0; kk < 2; kk++) {
#pragma unroll
      for (int i = 0; i < FM; i++) {
        int r = wm + i * 16 + lo;
        af[kk][i] = *(const half8*)&As[r * 64 + ((kk * 4 + q) ^ (r & 7)) * 8];
      }
#pragma unroll
      for (int j = 0; j < FN; j++) {
        int n = wn + j * 16 + lo;
        bf[kk][j] = *(const half8*)&Bs[n * 64 + ((kk * 4 + q) ^ (n & 7)) * 8];
      }
    }
#pragma unroll
    for (int kk = 0; kk < 2; kk++)
#pragma unroll
      for (int i = 0; i < FM; i++)
#pragma unroll
        for (int j = 0; j < FN; j++)
          acc[i][j] = __builtin_amdgcn_mfma_f32_16x16x32_f16(af[kk][i], bf[kk][j], acc[i][j], 0, 0, 0);
  };

  // 2-phase pipeline: stage(next) issued before compute(cur); one barrier per K-step.
  stage(A0, B0, kb);
  __syncthreads();
  for (int k0 = kb; k0 < kEnd; k0 += 128) {
    if (k0 + 64 < kEnd) stage(A1, B1, k0 + 64);
    compute(A0, B0);
    __syncthreads();
    if (k0 + 64 < kEnd) {
      if (k0 + 128 < kEnd) stage(A0, B0, k0 + 128);
      compute(A1, B1);
      __syncthreads();
    }
  }

#pragma unroll
  for (int i = 0; i < FM; i++) {
#pragma unroll
    for (int j = 0; j < FN; j++) {
      int col = n0 + wn + j * 16 + lo;
      if (p.c_tr) {  // transposed f16 store: 4 consecutive rows -> one 8B store
        int row0 = m0 + wm + i * 16 + q * 4;
        union { f16 h[4]; uint2 u; } o;
#pragma unroll
        for (int r = 0; r < 4; r++) {
          float v = acc[i][j][r];
          if (p.bias) v += p.bias[biasoff + col];
          v *= p.alpha;
          o.h[r] = (f16)v;
        }
        *(uint2*)&p.Ch[coff + (long)col * p.c_row + row0] = o.u;
      } else {
#pragma unroll
        for (int r = 0; r < 4; r++) {
          int row = m0 + wm + i * 16 + q * 4 + r;
          if (row < Meff) {
            long rr = gl ? (long)gl[row] : (long)row;
            float v = acc[i][j][r];
            if (p.bias) v += p.bias[biasoff + col];
            v *= p.alpha;
            if (p.res) v += p.res[roff + rr * p.res_row + col];
            if (p.gelu) v = 0.5f * v * (1.0f + erff(v * 0.70710678118654752f));
            long ci = coff + rr * p.c_row + col;
            if (p.Cf) p.Cf[ci] = v;
            else p.Ch[ci] = (f16)v;
          }
        }
      }
    }
  }
}

template <int BM, int BN>
__global__ __launch_bounds__(256) void gemm_t(GemmP p) {
  __shared__ f16 A0[BM * 64], A1[BM * 64], B0[BN * 64], B1[BN * 64];
  int l = xcd_swz(blockIdx.x, gridDim.x);
  int bx = l % p.gx;
  int r = l / p.gx;
  int by = r % p.gy;
  int bz = r / p.gy;
  gemm_body<BM, BN>(p, bx, by, bz, A0, A1, B0, B1);
}

// fused Q/K/V projections: one flat grid, block ranges per sub-GEMM (128x128 tiles)
struct Multi3P {
  GemmP g0, g1, g2;
  int n0, n1;
  int gx0, gy0, gx1, gy1, gx2, gy2;
};

__global__ __launch_bounds__(256) void gemm_qkv(Multi3P mp) {
  __shared__ f16 A0[128 * 64], A1[128 * 64], B0[128 * 64], B1[128 * 64];
  int fb = xcd_swz(blockIdx.x, gridDim.x);
  if (fb < mp.n0) {
    gemm_body<128, 128>(mp.g0, fb % mp.gx0, (fb / mp.gx0) % mp.gy0, fb / (mp.gx0 * mp.gy0),
                        A0, A1, B0, B1);
    return;
  }
  fb -= mp.n0;
  if (fb < mp.n1) {
    gemm_body<128, 128>(mp.g1, fb % mp.gx1, (fb / mp.gx1) % mp.gy1, fb / (mp.gx1 * mp.gy1),
                        A0, A1, B0, B1);
    return;
  }
  fb -= mp.n1;
  gemm_body<128, 128>(mp.g2, fb % mp.gx2, (fb / mp.gx2) % mp.gy2, fb / (mp.gx2 * mp.gy2),
                      A0, A1, B0, B1);
}

extern "C" void kernel_launch(void* const* d_in, const int* in_sizes, int n_in,
                              void* d_out, int out_size, void* d_ws, size_t ws_size,
                              hipStream_t stream) {
  const float* concated = (const float*)d_in[0];
  const float* gen      = (const float*)d_in[1];
  const float* mask     = (const float*)d_in[2];
  const float* ln_g     = (const float*)d_in[3];
  const float* ln_b     = (const float*)d_in[4];
  const float* wq = (const float*)d_in[5];  const float* bq = (const float*)d_in[6];
  const float* wk = (const float*)d_in[7];  const float* bk = (const float*)d_in[8];
  const float* wv = (const float*)d_in[9];  const float* bv = (const float*)d_in[10];
  const float* wo = (const float*)d_in[11]; const float* bo = (const float*)d_in[12];
  const float* gw = (const float*)d_in[13]; const float* gb = (const float*)d_in[14];
  const float* w1 = (const float*)d_in[15]; const float* b1 = (const float*)d_in[16];
  const float* w2 = (const float*)d_in[17]; const float* b2 = (const float*)d_in[18];
  float* out = (float*)d_out;

  size_t off = 0;
  auto alloc = [&](size_t bytes) -> void* {
    void* p = (char*)d_ws + off;
    off += (bytes + 255) & ~(size_t)255;
    return p;
  };
  f16* wq_t  = (f16*)alloc((size_t)kH * kH * 2);       // [N][K]
  f16* wk_t  = (f16*)alloc((size_t)kH * kH * 2);
  f16* wv_t  = (f16*)alloc((size_t)kH * kH * 2);
  f16* wo_t  = (f16*)alloc((size_t)kH * kH * 2);
  f16* w1_t  = (f16*)alloc((size_t)kE * kH * kDFF * 2);  // [E][DFF][H]
  f16* w2_t  = (f16*)alloc((size_t)kE * kDFF * kH * 2);  // [E][H][DFF]
  f16* lnc_h = (f16*)alloc((size_t)kB * kSK * kH * 2);
  f16* lng_h = (f16*)alloc((size_t)kTok * kH * 2);
  f16* q_h   = (f16*)alloc((size_t)kTok * kH * 2);
  f16* k_h   = (f16*)alloc((size_t)kB * kSK * kH * 2);
  f16* v_t   = (f16*)alloc((size_t)kB * kSK * kH * 2);   // [b][h][d][sk]
  f16* ctx_h = (f16*)alloc((size_t)kTok * kH * 2);
  float* ca_f   = (float*)alloc((size_t)kTok * kH * 4);
  float* lnca_f = (float*)alloc((size_t)kTok * kH * 4);
  f16* lnca_h   = (f16*)alloc((size_t)kTok * kH * 2);
  f16* h1_h     = (f16*)alloc((size_t)kTok * kDFF * 2);
  float* part_f = (float*)alloc((size_t)4 * kTok * kH * 4);
  int* cnt_d    = (int*)alloc(kE * 4);
  int* list_d   = (int*)alloc((size_t)kE * kTok * 4);
  int* eid_d    = (int*)alloc((size_t)kTok * 4);

  // ---- weight transpose-convert fp32 [K][N] -> fp16 [N][K] ----
  {
    Tr4P tp{wq, wk, wv, wo, wq_t, wk_t, wv_t, wo_t};
    tr_f2h4<<<dim3(32, 32, 4), 256, 0, stream>>>(tp);
  }
  tr_f2h<<<dim3(kDFF / 32, kH / 32, kE), 256, 0, stream>>>(w1, w1_t, kH, kDFF);
  tr_f2h<<<dim3(kH / 32, kDFF / 32, kE), 256, 0, stream>>>(w2, w2_t, kDFF, kH);

  // ---- LayerNorms of inputs ----
  ln_kernel<<<kB * kSK, 256, 0, stream>>>(concated, ln_g, ln_b, lnc_h, nullptr, kB * kSK);
  ln_kernel<<<kTok, 256, 0, stream>>>(gen, ln_g, ln_b, lng_h, nullptr, kTok);

  // ---- fused Q/K/V projections (one launch, 640 blocks at 128x128) ----
  {
    Multi3P mp{};
    GemmP& pq = mp.g0;
    pq.A = lng_h; pq.a_row = kH; pq.Bm = wq_t; pq.b_nstr = kH;
    pq.Ch = q_h; pq.c_row = kH; pq.bias = bq; pq.alpha = 0.125f;
    pq.M = kTok; pq.N = kH; pq.K = kH; pq.zdiv = 1;
    GemmP& pk = mp.g1;
    pk.A = lnc_h; pk.a_row = kH; pk.Bm = wk_t; pk.b_nstr = kH;
    pk.Ch = k_h; pk.c_row = kH; pk.bias = bk; pk.alpha = 1.0f;
    pk.M = kB * kSK; pk.N = kH; pk.K = kH; pk.zdiv = 1;
    GemmP& pv = mp.g2;
    pv.A = lnc_h; pv.a_row = kH; pv.a_z1 = (long)kSK * kH;
    pv.Bm = wv_t; pv.b_nstr = kH;
    pv.Ch = v_t; pv.c_row = kSK; pv.c_z1 = (long)kH * kSK; pv.c_tr = 1;
    pv.bias = bv; pv.alpha = 1.0f;
    pv.M = kSK; pv.N = kH; pv.K = kH; pv.zdiv = 1;
    mp.gx0 = kH / 128; mp.gy0 = kTok / 128;        mp.n0 = mp.gx0 * mp.gy0;       // 128
    mp.gx1 = kH / 128; mp.gy1 = (kB * kSK) / 128;  mp.n1 = mp.gx1 * mp.gy1;       // 256
    mp.gx2 = kH / 128; mp.gy2 = kSK / 128;                                         // x8, z=4
    int ntot = mp.n0 + mp.n1 + mp.gx2 * mp.gy2 * kB;                               // 640
    gemm_qkv<<<dim3(ntot), 256, 0, stream>>>(mp);
  }
  // ---- fused flash attention -> ctx_h (1D grid, XCD swizzle) ----
  flash_kernel<<<dim3((kSQ / 64) * kB * kHeads), 256, 0, stream>>>(q_h, k_h, v_t, mask, ctx_h);
  // ---- ca_out = ctx @ wo^T + bo + gen (fp32 out) ----
  {
    GemmP p{}; p.A = ctx_h; p.a_row = kH;
    p.Bm = wo_t; p.b_nstr = kH;
    p.Cf = ca_f; p.c_row = kH; p.bias = bo;
    p.res = gen; p.res_row = kH;
    p.alpha = 1.0f; p.M = kTok; p.N = kH; p.K = kH; p.zdiv = 1;
    p.gx = kH / 64; p.gy = kTok / 64;
    gemm_t<64, 64><<<dim3(p.gx * p.gy), 256, 0, stream>>>(p);
  }
  // ---- ln_ca (fp32 + fp16) ----
  ln_kernel<<<kTok, 256, 0, stream>>>(ca_f, ln_g, ln_b, lnca_h, lnca_f, kTok);
  // ---- router + expert bucketing ----
  zero_kernel<<<1, 64, 0, stream>>>(cnt_d, kE);
  router_kernel<<<kTok, 64, 0, stream>>>(ca_f, gw, gb, cnt_d, list_d, eid_d);
  // ---- FFN1: h1 = gelu(ln_ca @ w1[e] + b1[e]) ; 128x128 tile ----
  {
    GemmP p{}; p.A = lnca_h; p.a_row = kH;
    p.Bm = w1_t; p.b_nstr = kH; p.b_z2 = (long)kH * kDFF;
    p.Ch = h1_h; p.c_row = kDFF; p.bias = b1; p.bias_z = kDFF;
    p.alpha = 1.0f; p.gelu = 1; p.M = kTok; p.N = kDFF; p.K = kH; p.zdiv = 1;
    p.glist = list_d; p.cnt = cnt_d;
    p.gx = kDFF / 128; p.gy = kTok / 128;
    gemm_t<128, 128><<<dim3(p.gx * p.gy * kE), 256, 0, stream>>>(p);
  }
  // ---- FFN2: part[s] = h1 @ w2[e] (split-K x4, fp32 partials, no atomics) ----
  {
    GemmP p{}; p.A = h1_h; p.a_row = kDFF;
    p.Bm = w2_t; p.b_nstr = kDFF; p.b_z2 = (long)kDFF * kH;
    p.Cf = part_f; p.c_row = kH; p.c_split = (long)kTok * kH;
    p.alpha = 1.0f; p.ksplit = 4;
    p.M = kTok; p.N = kH; p.K = kDFF; p.zdiv = 1;
    p.glist = list_d; p.cnt = cnt_d;
    p.gx = kH / 128; p.gy = kTok / 128;
    gemm_t<128, 128><<<dim3(p.gx * p.gy * kE * 4), 256, 0, stream>>>(p);
  }
  // ---- reduce: out = sum(part) + b2[eid] + lnca ----
  ffn2_reduce<<<kTok, 256, 0, stream>>>(part_f, lnca_f, b2, eid_d, out);
}

// Round 10
// 625.075 us; speedup vs baseline: 1.1660x; 1.1038x over previous
//
#include <hip/hip_runtime.h>
#include <stdint.h>
#include <stddef.h>

typedef _Float16 f16;
typedef _Float16 half8 __attribute__((ext_vector_type(8)));
typedef float f32x4 __attribute__((ext_vector_type(4)));

constexpr int kB = 4, kSQ = 512, kSK = 1024, kH = 1024, kHeads = 16, kE = 8, kDFF = 4096;
constexpr int kTok = kB * kSQ;  // 2048 gen tokens

// async global->LDS, 16B per lane; LDS dest must be wave-uniform base + lane*16
__device__ __forceinline__ void g2l16(const f16* g, f16* l) {
  __builtin_amdgcn_global_load_lds((const __attribute__((address_space(1))) uint32_t*)g,
                                   (__attribute__((address_space(3))) uint32_t*)l, 16, 0, 0);
}

// bijective XCD chunk swizzle (T1): physical round-robin -> contiguous logical
// chunk per XCD. Requires nwg % 8 == 0 (all our grids are).
__device__ __forceinline__ int xcd_swz(int phys, int nwg) {
  return (phys & 7) * (nwg >> 3) + (phys >> 3);
}

// ---------------- transpose + fp32->fp16: dst[C][R] = (f16)src[R][C], batched over z
__global__ __launch_bounds__(256) void tr_f2h(const float* __restrict__ src,
                                              f16* __restrict__ dst, int R, int C) {
  __shared__ float t[32][33];
  long zo = (long)blockIdx.z * R * C;
  int r0 = blockIdx.y * 32, c0 = blockIdx.x * 32;
  int tr = threadIdx.x >> 3, tc = (threadIdx.x & 7) << 2;
  float4 v = *(const float4*)(src + zo + (long)(r0 + tr) * C + c0 + tc);
  t[tr][tc] = v.x; t[tr][tc + 1] = v.y; t[tr][tc + 2] = v.z; t[tr][tc + 3] = v.w;
  __syncthreads();
  union { f16 h[4]; uint2 u; } o;
  o.h[0] = (f16)t[tc + 0][tr]; o.h[1] = (f16)t[tc + 1][tr];
  o.h[2] = (f16)t[tc + 2][tr]; o.h[3] = (f16)t[tc + 3][tr];
  *(uint2*)(dst + zo + (long)(c0 + tr) * R + r0 + tc) = o.u;
}

// four 1024x1024 weight transposes in one launch (z selects matrix)
struct Tr4P { const float* s0; const float* s1; const float* s2; const float* s3;
              f16* d0; f16* d1; f16* d2; f16* d3; };
__global__ __launch_bounds__(256) void tr_f2h4(Tr4P tp) {
  __shared__ float t[32][33];
  int z = blockIdx.z;
  const float* src = z == 0 ? tp.s0 : z == 1 ? tp.s1 : z == 2 ? tp.s2 : tp.s3;
  f16* dst = z == 0 ? tp.d0 : z == 1 ? tp.d1 : z == 2 ? tp.d2 : tp.d3;
  int r0 = blockIdx.y * 32, c0 = blockIdx.x * 32;
  int tr = threadIdx.x >> 3, tc = (threadIdx.x & 7) << 2;
  float4 v = *(const float4*)(src + (long)(r0 + tr) * kH + c0 + tc);
  t[tr][tc] = v.x; t[tr][tc + 1] = v.y; t[tr][tc + 2] = v.z; t[tr][tc + 3] = v.w;
  __syncthreads();
  union { f16 h[4]; uint2 u; } o;
  o.h[0] = (f16)t[tc + 0][tr]; o.h[1] = (f16)t[tc + 1][tr];
  o.h[2] = (f16)t[tc + 2][tr]; o.h[3] = (f16)t[tc + 3][tr];
  *(uint2*)(dst + (long)(c0 + tr) * kH + r0 + tc) = o.u;
}

// ---------------- LayerNorm over H=1024, one block (256 thr) per row --------
__global__ __launch_bounds__(256) void ln_kernel(const float* __restrict__ x,
                                                 const float* __restrict__ g,
                                                 const float* __restrict__ b,
                                                 f16* __restrict__ oh, float* __restrict__ of,
                                                 int rows) {
  int row = blockIdx.x;
  if (row >= rows) return;
  int tid = threadIdx.x;
  const float* xr = x + (long)row * kH;
  float4 v = *(const float4*)(xr + tid * 4);
  float s = v.x + v.y + v.z + v.w;
  float s2 = v.x * v.x + v.y * v.y + v.z * v.z + v.w * v.w;
  __shared__ float red[8];
  for (int o = 32; o; o >>= 1) { s += __shfl_down(s, o); s2 += __shfl_down(s2, o); }
  int wv = tid >> 6, lane = tid & 63;
  if (lane == 0) { red[wv] = s; red[4 + wv] = s2; }
  __syncthreads();
  if (tid == 0) {
    red[0] = red[0] + red[1] + red[2] + red[3];
    red[4] = red[4] + red[5] + red[6] + red[7];
  }
  __syncthreads();
  float mean = red[0] * (1.0f / kH);
  float var = red[4] * (1.0f / kH) - mean * mean;
  float rs = rsqrtf(var + 1e-6f);
  float4 gv = *(const float4*)(g + tid * 4);
  float4 bv = *(const float4*)(b + tid * 4);
  float y0 = (v.x - mean) * rs * gv.x + bv.x;
  float y1 = (v.y - mean) * rs * gv.y + bv.y;
  float y2 = (v.z - mean) * rs * gv.z + bv.z;
  float y3 = (v.w - mean) * rs * gv.w + bv.w;
  long base = (long)row * kH + tid * 4;
  if (oh) {
    union { f16 h[4]; uint2 u; } o;
    o.h[0] = (f16)y0; o.h[1] = (f16)y1; o.h[2] = (f16)y2; o.h[3] = (f16)y3;
    *(uint2*)(oh + base) = o.u;
  }
  if (of) { float4 o4 = {y0, y1, y2, y3}; *(float4*)(of + base) = o4; }
}

__global__ void zero_kernel(int* __restrict__ p, int n) {
  int i = blockIdx.x * blockDim.x + threadIdx.x;
  if (i < n) p[i] = 0;
}

// ---------------- router: fp32 logits, first-index argmax, bucket tokens ----
__global__ __launch_bounds__(64) void router_kernel(const float* __restrict__ ca,
                                                    const float* __restrict__ gw,
                                                    const float* __restrict__ gb,
                                                    int* __restrict__ cursors,
                                                    int* __restrict__ list,
                                                    int* __restrict__ eid) {
  int t = blockIdx.x;
  int lane = threadIdx.x;
  const float* x = ca + (long)t * kH;
  float acc[kE];
#pragma unroll
  for (int e = 0; e < kE; e++) acc[e] = 0.0f;
  for (int h = lane; h < kH; h += 64) {
    float xv = x[h];
    const float* gr = gw + (long)h * kE;
#pragma unroll
    for (int e = 0; e < kE; e++) acc[e] += xv * gr[e];
  }
#pragma unroll
  for (int e = 0; e < kE; e++)
    for (int o = 32; o; o >>= 1) acc[e] += __shfl_down(acc[e], o);
  if (lane == 0) {
    int best = 0;
    float bv = acc[0] + gb[0];
    for (int e = 1; e < kE; e++) {
      float v = acc[e] + gb[e];
      if (v > bv) { bv = v; best = e; }  // strict > == first-index argmax
    }
    int slot = atomicAdd(&cursors[best], 1);
    list[best * kTok + slot] = t;
    eid[t] = best;
  }
}

// ---------------- FFN2 reduce: out = sum(part[0..3]) + b2[eid] + lnca --------
__global__ __launch_bounds__(256) void ffn2_reduce(const float* __restrict__ part,
                                                   const float* __restrict__ lnca,
                                                   const float* __restrict__ b2,
                                                   const int* __restrict__ eid,
                                                   float* __restrict__ out) {
  int t = blockIdx.x;
  int i = threadIdx.x * 4;
  int e = eid[t];
  long idx = (long)t * kH + i;
  float4 p0 = *(const float4*)(part + idx);
  float4 p1 = *(const float4*)(part + (long)kTok * kH + idx);
  float4 p2 = *(const float4*)(part + 2L * kTok * kH + idx);
  float4 p3 = *(const float4*)(part + 3L * kTok * kH + idx);
  float4 r  = *(const float4*)(lnca + idx);
  float4 bb = *(const float4*)(b2 + (long)e * kH + i);
  float4 o = {p0.x + p1.x + p2.x + p3.x + r.x + bb.x,
              p0.y + p1.y + p2.y + p3.y + r.y + bb.y,
              p0.z + p1.z + p2.z + p3.z + r.z + bb.z,
              p0.w + p1.w + p2.w + p3.w + r.w + bb.w};
  *(float4*)(out + idx) = o;
}

// ---------------- fused flash attention ----------------
// K/V staged row-contiguous (8 lanes per 128B row), XOR-swizzled source+read.
__global__ __launch_bounds__(256) void flash_kernel(const f16* __restrict__ q,
                                                    const f16* __restrict__ k,
                                                    const f16* __restrict__ v_t,
                                                    const float* __restrict__ mask,
                                                    f16* __restrict__ ctx) {
  __shared__ f16 Ks[64 * 64];
  __shared__ f16 Vs[64 * 64];
  __shared__ f16 Ps[4][16][72];  // pitch 72 (144B) breaks write conflicts
  int l = xcd_swz(blockIdx.x, gridDim.x);
  int qt = l & 7;          // kSQ/64 = 8 q-tiles, fastest
  int bh = l >> 3;
  int b = bh >> 4;
  int ho = (bh & 15) * 64;
  int tid = threadIdx.x, lane = tid & 63, wave = tid >> 6;
  int quad = lane >> 4, lo = lane & 15;

  long qg = ((long)b * kSQ + qt * 64 + wave * 16 + lo) * kH + ho;
  half8 aq0 = *(const half8*)(q + qg + quad * 8);
  half8 aq1 = *(const half8*)(q + qg + 32 + quad * 8);

  int srow = tid >> 3;                       // 0..31 within group
  int soct = (tid & 7) ^ (srow & 7);         // swizzled k/sk octet
  const f16* ksrc[2];
  const f16* vsrc[2];
#pragma unroll
  for (int s = 0; s < 2; s++) {
    int r = s * 32 + srow;
    ksrc[s] = k + ((long)b * kSK + r) * kH + ho + soct * 8;       // row = key
    vsrc[s] = v_t + ((long)bh * 64 + r) * kSK + soct * 8;         // row = d
  }
  const float* maskp = mask + ((long)b * kSQ + qt * 64 + wave * 16 + quad * 4) * kSK;

  float m_s[4] = {-1e30f, -1e30f, -1e30f, -1e30f};
  float l_s[4] = {0.f, 0.f, 0.f, 0.f};
  f32x4 O[4] = {};

  for (int kt = 0; kt < kSK / 64; kt++) {
    int sk0 = kt * 64;
#pragma unroll
    for (int s = 0; s < 2; s++) g2l16(ksrc[s] + (long)sk0 * kH, &Ks[(s * 256 + tid) * 8]);
#pragma unroll
    for (int s = 0; s < 2; s++) g2l16(vsrc[s] + sk0, &Vs[(s * 256 + tid) * 8]);
    __syncthreads();
    f32x4 sf[4] = {};
#pragma unroll
    for (int nt = 0; nt < 4; nt++) {
      int key = nt * 16 + lo;
      half8 bk0 = *(const half8*)&Ks[key * 64 + (((0 * 4 + quad)) ^ (key & 7)) * 8];
      half8 bk1 = *(const half8*)&Ks[key * 64 + (((1 * 4 + quad)) ^ (key & 7)) * 8];
      sf[nt] = __builtin_amdgcn_mfma_f32_16x16x32_f16(aq0, bk0, sf[nt], 0, 0, 0);
      sf[nt] = __builtin_amdgcn_mfma_f32_16x16x32_f16(aq1, bk1, sf[nt], 0, 0, 0);
    }
#pragma unroll
    for (int r = 0; r < 4; r++)
#pragma unroll
      for (int nt = 0; nt < 4; nt++)
        sf[nt][r] += maskp[(long)r * kSK + sk0 + nt * 16 + lo];
#pragma unroll
    for (int r = 0; r < 4; r++) {
      float mx = fmaxf(fmaxf(sf[0][r], sf[1][r]), fmaxf(sf[2][r], sf[3][r]));
      mx = fmaxf(mx, __shfl_xor(mx, 1));
      mx = fmaxf(mx, __shfl_xor(mx, 2));
      mx = fmaxf(mx, __shfl_xor(mx, 4));
      mx = fmaxf(mx, __shfl_xor(mx, 8));
      float m_new = fmaxf(m_s[r], mx);
      float alpha = __expf(m_s[r] - m_new);
      m_s[r] = m_new;
      float p0 = __expf(sf[0][r] - m_new), p1 = __expf(sf[1][r] - m_new);
      float p2 = __expf(sf[2][r] - m_new), p3 = __expf(sf[3][r] - m_new);
      float rs = p0 + p1 + p2 + p3;
      rs += __shfl_xor(rs, 1);
      rs += __shfl_xor(rs, 2);
      rs += __shfl_xor(rs, 4);
      rs += __shfl_xor(rs, 8);
      l_s[r] = l_s[r] * alpha + rs;
#pragma unroll
      for (int nt = 0; nt < 4; nt++) O[nt][r] *= alpha;
      Ps[wave][quad * 4 + r][0 * 16 + lo] = (f16)p0;
      Ps[wave][quad * 4 + r][1 * 16 + lo] = (f16)p1;
      Ps[wave][quad * 4 + r][2 * 16 + lo] = (f16)p2;
      Ps[wave][quad * 4 + r][3 * 16 + lo] = (f16)p3;
    }
    half8 ap0 = *(const half8*)&Ps[wave][lo][quad * 8];
    half8 ap1 = *(const half8*)&Ps[wave][lo][32 + quad * 8];
#pragma unroll
    for (int nt = 0; nt < 4; nt++) {
      int d = nt * 16 + lo;
      half8 bv0 = *(const half8*)&Vs[d * 64 + (((0 * 4 + quad)) ^ (d & 7)) * 8];
      half8 bv1 = *(const half8*)&Vs[d * 64 + (((1 * 4 + quad)) ^ (d & 7)) * 8];
      O[nt] = __builtin_amdgcn_mfma_f32_16x16x32_f16(ap0, bv0, O[nt], 0, 0, 0);
      O[nt] = __builtin_amdgcn_mfma_f32_16x16x32_f16(ap1, bv1, O[nt], 0, 0, 0);
    }
    __syncthreads();
  }
#pragma unroll
  for (int r = 0; r < 4; r++) {
    float inv = 1.0f / l_s[r];
    long row = (long)b * kSQ + qt * 64 + wave * 16 + quad * 4 + r;
#pragma unroll
    for (int nt = 0; nt < 4; nt++)
      ctx[row * kH + ho + nt * 16 + lo] = (f16)(O[nt][r] * inv);
  }
}

// ---------------- tiled fp16 MFMA GEMM, BK=64, 512 thr / 8 waves (2x4) ------
// C[M,N] = epilogue(A[M,K] @ B[N,K]^T); B is [N][K] k-contiguous.
// 8 waves raise waves/SIMD to 4 under grid-limited working sets.
// Per-wave tile (BM/2)x(BN/4); FM=BM/32, FN=BN/64 16x16 frags.
// Row-contiguous staging (8 lanes per 128B row), XOR-swizzled source + reads.
// 2-phase dbuf; 1D grid + XCD chunk swizzle.
struct GemmP {
  const f16* A; long a_row, a_z1, a_z2;
  const f16* Bm; long b_nstr, b_z1, b_z2;
  float* Cf; f16* Ch; long c_row, c_z1, c_z2, c_split; int c_tr;
  const float* bias; long bias_z;
  const float* res; long res_row, res_z1, res_z2;
  float alpha; int gelu; int ksplit;
  int M, N, K, zdiv;
  int gx, gy;  // logical grid dims (z = rest)
  const int* glist; const int* cnt;  // expert-gather mode: z = expert
};

template <int BM, int BN>
__device__ __forceinline__ void gemm_body(const GemmP& p, int bx, int by, int bz,
                                          f16* A0, f16* A1, f16* B0, f16* B1) {
  constexpr int FM = BM / 32, FN = BN / 64;
  constexpr int SA = BM / 64, SB = BN / 64;  // staging iters (512 thr)
  int z = bz;
  int kb = 0, kEnd = p.K, ks = 0;
  if (p.ksplit > 1) {
    int kc = p.K / p.ksplit;
    ks = z % p.ksplit;
    kb = ks * kc;
    kEnd = kb + kc;
    z /= p.ksplit;
  }
  long aoff = 0, boff = 0, coff = 0, roff = 0, biasoff = 0;
  const int* gl = nullptr;
  int Meff = p.M;
  if (p.glist) {
    Meff = p.cnt[z];
    gl = p.glist + (long)z * kTok;
    boff = (long)z * p.b_z2;
    biasoff = (long)z * p.bias_z;
  } else {
    int z1 = z / p.zdiv, z2 = z % p.zdiv;
    aoff = (long)z1 * p.a_z1 + (long)z2 * p.a_z2;
    boff = (long)z1 * p.b_z1 + (long)z2 * p.b_z2;
    coff = (long)z1 * p.c_z1 + (long)z2 * p.c_z2;
    roff = (long)z1 * p.res_z1 + (long)z2 * p.res_z2;
  }
  coff += (long)ks * p.c_split;
  int m0 = by * BM;
  if (m0 >= Meff) return;
  int n0 = bx * BN;
  int tid = threadIdx.x, lane = tid & 63, wave = tid >> 6;   // wave 0..7
  int wm = (wave & 1) * (BM / 2), wn = (wave >> 1) * (BN / 4);
  int q = lane >> 4, lo = lane & 15;

  // row-contiguous staging: chunk c = s*512+tid -> row = s*64 + (tid>>3),
  // source k-octet = (tid&7) ^ (row&7); LDS dest linear -> [row][slot].
  int srow = tid >> 3;
  int soct = (tid & 7) ^ (srow & 7);
  const f16* asrc[SA];
  const f16* bsrc[SB];
#pragma unroll
  for (int s = 0; s < SA; s++) {
    int row = m0 + s * 64 + srow;
    if (gl) row = gl[row < Meff ? row : Meff - 1];  // clamp: garbage rows never stored
    asrc[s] = p.A + aoff + (long)row * p.a_row + soct * 8;
  }
#pragma unroll
  for (int s = 0; s < SB; s++)
    bsrc[s] = p.Bm + boff + (long)(n0 + s * 64 + srow) * p.b_nstr + soct * 8;

  f32x4 acc[FM][FN] = {};

  auto stage = [&](f16* Ad, f16* Bd, int k0) {
#pragma unroll
    for (int s = 0; s < SA; s++) g2l16(asrc[s] + k0, &Ad[(s * 512 + tid) * 8]);
#pragma unroll
    for (int s = 0; s < SB; s++) g2l16(bsrc[s] + k0, &Bd[(s * 512 + tid) * 8]);
  };
  auto compute = [&](const f16* As, const f16* Bs) {
    half8 af[2][FM], bf[2][FN];
#pragma unroll
    for (int kk = 0; kk < 2; kk++) {
#pragma unroll
      for (int i = 0; i < FM; i++) {
        int r = wm + i * 16 + lo;
        af[kk][i] = *(const half8*)&As[r * 64 + ((kk * 4 + q) ^ (r & 7)) * 8];
      }
#pragma unroll
      for (int j = 0; j < FN; j++) {
        int n = wn + j * 16 + lo;
        bf[kk][j] = *(const half8*)&Bs[n * 64 + ((kk * 4 + q) ^ (n & 7)) * 8];
      }
    }
#pragma unroll
    for (int kk = 0; kk < 2; kk++)
#pragma unroll
      for (int i = 0; i < FM; i++)
#pragma unroll
        for (int j = 0; j < FN; j++)
          acc[i][j] = __builtin_amdgcn_mfma_f32_16x16x32_f16(af[kk][i], bf[kk][j], acc[i][j], 0, 0, 0);
  };

  // 2-phase pipeline: stage(next) issued before compute(cur); one barrier per K-step.
  stage(A0, B0, kb);
  __syncthreads();
  for (int k0 = kb; k0 < kEnd; k0 += 128) {
    if (k0 + 64 < kEnd) stage(A1, B1, k0 + 64);
    compute(A0, B0);
    __syncthreads();
    if (k0 + 64 < kEnd) {
      if (k0 + 128 < kEnd) stage(A0, B0, k0 + 128);
      compute(A1, B1);
      __syncthreads();
    }
  }

#pragma unroll
  for (int i = 0; i < FM; i++) {
#pragma unroll
    for (int j = 0; j < FN; j++) {
      int col = n0 + wn + j * 16 + lo;
      if (p.c_tr) {  // transposed f16 store: 4 consecutive rows -> one 8B store
        int row0 = m0 + wm + i * 16 + q * 4;
        union { f16 h[4]; uint2 u; } o;
#pragma unroll
        for (int r = 0; r < 4; r++) {
          float v = acc[i][j][r];
          if (p.bias) v += p.bias[biasoff + col];
          v *= p.alpha;
          o.h[r] = (f16)v;
        }
        *(uint2*)&p.Ch[coff + (long)col * p.c_row + row0] = o.u;
      } else {
#pragma unroll
        for (int r = 0; r < 4; r++) {
          int row = m0 + wm + i * 16 + q * 4 + r;
          if (row < Meff) {
            long rr = gl ? (long)gl[row] : (long)row;
            float v = acc[i][j][r];
            if (p.bias) v += p.bias[biasoff + col];
            v *= p.alpha;
            if (p.res) v += p.res[roff + rr * p.res_row + col];
            if (p.gelu) v = 0.5f * v * (1.0f + erff(v * 0.70710678118654752f));
            long ci = coff + rr * p.c_row + col;
            if (p.Cf) p.Cf[ci] = v;
            else p.Ch[ci] = (f16)v;
          }
        }
      }
    }
  }
}

template <int BM, int BN>
__global__ __launch_bounds__(512) void gemm_t(GemmP p) {
  __shared__ f16 A0[BM * 64], A1[BM * 64], B0[BN * 64], B1[BN * 64];
  int l = xcd_swz(blockIdx.x, gridDim.x);
  int bx = l % p.gx;
  int r = l / p.gx;
  int by = r % p.gy;
  int bz = r / p.gy;
  gemm_body<BM, BN>(p, bx, by, bz, A0, A1, B0, B1);
}

// fused Q/K/V projections: one flat grid, block ranges per sub-GEMM (128x128 tiles)
struct Multi3P {
  GemmP g0, g1, g2;
  int n0, n1;
  int gx0, gy0, gx1, gy1, gx2, gy2;
};

__global__ __launch_bounds__(512) void gemm_qkv(Multi3P mp) {
  __shared__ f16 A0[128 * 64], A1[128 * 64], B0[128 * 64], B1[128 * 64];
  int fb = xcd_swz(blockIdx.x, gridDim.x);
  if (fb < mp.n0) {
    gemm_body<128, 128>(mp.g0, fb % mp.gx0, (fb / mp.gx0) % mp.gy0, fb / (mp.gx0 * mp.gy0),
                        A0, A1, B0, B1);
    return;
  }
  fb -= mp.n0;
  if (fb < mp.n1) {
    gemm_body<128, 128>(mp.g1, fb % mp.gx1, (fb / mp.gx1) % mp.gy1, fb / (mp.gx1 * mp.gy1),
                        A0, A1, B0, B1);
    return;
  }
  fb -= mp.n1;
  gemm_body<128, 128>(mp.g2, fb % mp.gx2, (fb / mp.gx2) % mp.gy2, fb / (mp.gx2 * mp.gy2),
                      A0, A1, B0, B1);
}

extern "C" void kernel_launch(void* const* d_in, const int* in_sizes, int n_in,
                              void* d_out, int out_size, void* d_ws, size_t ws_size,
                              hipStream_t stream) {
  const float* concated = (const float*)d_in[0];
  const float* gen      = (const float*)d_in[1];
  const float* mask     = (const float*)d_in[2];
  const float* ln_g     = (const float*)d_in[3];
  const float* ln_b     = (const float*)d_in[4];
  const float* wq = (const float*)d_in[5];  const float* bq = (const float*)d_in[6];
  const float* wk = (const float*)d_in[7];  const float* bk = (const float*)d_in[8];
  const float* wv = (const float*)d_in[9];  const float* bv = (const float*)d_in[10];
  const float* wo = (const float*)d_in[11]; const float* bo = (const float*)d_in[12];
  const float* gw = (const float*)d_in[13]; const float* gb = (const float*)d_in[14];
  const float* w1 = (const float*)d_in[15]; const float* b1 = (const float*)d_in[16];
  const float* w2 = (const float*)d_in[17]; const float* b2 = (const float*)d_in[18];
  float* out = (float*)d_out;

  size_t off = 0;
  auto alloc = [&](size_t bytes) -> void* {
    void* p = (char*)d_ws + off;
    off += (bytes + 255) & ~(size_t)255;
    return p;
  };
  f16* wq_t  = (f16*)alloc((size_t)kH * kH * 2);       // [N][K]
  f16* wk_t  = (f16*)alloc((size_t)kH * kH * 2);
  f16* wv_t  = (f16*)alloc((size_t)kH * kH * 2);
  f16* wo_t  = (f16*)alloc((size_t)kH * kH * 2);
  f16* w1_t  = (f16*)alloc((size_t)kE * kH * kDFF * 2);  // [E][DFF][H]
  f16* w2_t  = (f16*)alloc((size_t)kE * kDFF * kH * 2);  // [E][H][DFF]
  f16* lnc_h = (f16*)alloc((size_t)kB * kSK * kH * 2);
  f16* lng_h = (f16*)alloc((size_t)kTok * kH * 2);
  f16* q_h   = (f16*)alloc((size_t)kTok * kH * 2);
  f16* k_h   = (f16*)alloc((size_t)kB * kSK * kH * 2);
  f16* v_t   = (f16*)alloc((size_t)kB * kSK * kH * 2);   // [b][h][d][sk]
  f16* ctx_h = (f16*)alloc((size_t)kTok * kH * 2);
  float* ca_f   = (float*)alloc((size_t)kTok * kH * 4);
  float* lnca_f = (float*)alloc((size_t)kTok * kH * 4);
  f16* lnca_h   = (f16*)alloc((size_t)kTok * kH * 2);
  f16* h1_h     = (f16*)alloc((size_t)kTok * kDFF * 2);
  float* part_f = (float*)alloc((size_t)4 * kTok * kH * 4);
  int* cnt_d    = (int*)alloc(kE * 4);
  int* list_d   = (int*)alloc((size_t)kE * kTok * 4);
  int* eid_d    = (int*)alloc((size_t)kTok * 4);

  // ---- weight transpose-convert fp32 [K][N] -> fp16 [N][K] ----
  {
    Tr4P tp{wq, wk, wv, wo, wq_t, wk_t, wv_t, wo_t};
    tr_f2h4<<<dim3(32, 32, 4), 256, 0, stream>>>(tp);
  }
  tr_f2h<<<dim3(kDFF / 32, kH / 32, kE), 256, 0, stream>>>(w1, w1_t, kH, kDFF);
  tr_f2h<<<dim3(kH / 32, kDFF / 32, kE), 256, 0, stream>>>(w2, w2_t, kDFF, kH);

  // ---- LayerNorms of inputs ----
  ln_kernel<<<kB * kSK, 256, 0, stream>>>(concated, ln_g, ln_b, lnc_h, nullptr, kB * kSK);
  ln_kernel<<<kTok, 256, 0, stream>>>(gen, ln_g, ln_b, lng_h, nullptr, kTok);

  // ---- fused Q/K/V projections (one launch, 640 blocks at 128x128, 8 waves) ----
  {
    Multi3P mp{};
    GemmP& pq = mp.g0;
    pq.A = lng_h; pq.a_row = kH; pq.Bm = wq_t; pq.b_nstr = kH;
    pq.Ch = q_h; pq.c_row = kH; pq.bias = bq; pq.alpha = 0.125f;
    pq.M = kTok; pq.N = kH; pq.K = kH; pq.zdiv = 1;
    GemmP& pk = mp.g1;
    pk.A = lnc_h; pk.a_row = kH; pk.Bm = wk_t; pk.b_nstr = kH;
    pk.Ch = k_h; pk.c_row = kH; pk.bias = bk; pk.alpha = 1.0f;
    pk.M = kB * kSK; pk.N = kH; pk.K = kH; pk.zdiv = 1;
    GemmP& pv = mp.g2;
    pv.A = lnc_h; pv.a_row = kH; pv.a_z1 = (long)kSK * kH;
    pv.Bm = wv_t; pv.b_nstr = kH;
    pv.Ch = v_t; pv.c_row = kSK; pv.c_z1 = (long)kH * kSK; pv.c_tr = 1;
    pv.bias = bv; pv.alpha = 1.0f;
    pv.M = kSK; pv.N = kH; pv.K = kH; pv.zdiv = 1;
    mp.gx0 = kH / 128; mp.gy0 = kTok / 128;        mp.n0 = mp.gx0 * mp.gy0;       // 128
    mp.gx1 = kH / 128; mp.gy1 = (kB * kSK) / 128;  mp.n1 = mp.gx1 * mp.gy1;       // 256
    mp.gx2 = kH / 128; mp.gy2 = kSK / 128;                                         // x8, z=4
    int ntot = mp.n0 + mp.n1 + mp.gx2 * mp.gy2 * kB;                               // 640
    gemm_qkv<<<dim3(ntot), 512, 0, stream>>>(mp);
  }
  // ---- fused flash attention -> ctx_h (1D grid, XCD swizzle) ----
  flash_kernel<<<dim3((kSQ / 64) * kB * kHeads), 256, 0, stream>>>(q_h, k_h, v_t, mask, ctx_h);
  // ---- ca_out = ctx @ wo^T + bo + gen (fp32 out) ----
  {
    GemmP p{}; p.A = ctx_h; p.a_row = kH;
    p.Bm = wo_t; p.b_nstr = kH;
    p.Cf = ca_f; p.c_row = kH; p.bias = bo;
    p.res = gen; p.res_row = kH;
    p.alpha = 1.0f; p.M = kTok; p.N = kH; p.K = kH; p.zdiv = 1;
    p.gx = kH / 64; p.gy = kTok / 64;
    gemm_t<64, 64><<<dim3(p.gx * p.gy), 512, 0, stream>>>(p);
  }
  // ---- ln_ca (fp32 + fp16) ----
  ln_kernel<<<kTok, 256, 0, stream>>>(ca_f, ln_g, ln_b, lnca_h, lnca_f, kTok);
  // ---- router + expert bucketing ----
  zero_kernel<<<1, 64, 0, stream>>>(cnt_d, kE);
  router_kernel<<<kTok, 64, 0, stream>>>(ca_f, gw, gb, cnt_d, list_d, eid_d);
  // ---- FFN1: h1 = gelu(ln_ca @ w1[e] + b1[e]) ; 128x128 tile, 8 waves ----
  {
    GemmP p{}; p.A = lnca_h; p.a_row = kH;
    p.Bm = w1_t; p.b_nstr = kH; p.b_z2 = (long)kH * kDFF;
    p.Ch = h1_h; p.c_row = kDFF; p.bias = b1; p.bias_z = kDFF;
    p.alpha = 1.0f; p.gelu = 1; p.M = kTok; p.N = kDFF; p.K = kH; p.zdiv = 1;
    p.glist = list_d; p.cnt = cnt_d;
    p.gx = kDFF / 128; p.gy = kTok / 128;
    gemm_t<128, 128><<<dim3(p.gx * p.gy * kE), 512, 0, stream>>>(p);
  }
  // ---- FFN2: part[s] = h1 @ w2[e] (split-K x4, fp32 partials, no atomics) ----
  {
    GemmP p{}; p.A = h1_h; p.a_row = kDFF;
    p.Bm = w2_t; p.b_nstr = kDFF; p.b_z2 = (long)kDFF * kH;
    p.Cf = part_f; p.c_row = kH; p.c_split = (long)kTok * kH;
    p.alpha = 1.0f; p.ksplit = 4;
    p.M = kTok; p.N = kH; p.K = kDFF; p.zdiv = 1;
    p.glist = list_d; p.cnt = cnt_d;
    p.gx = kH / 128; p.gy = kTok / 128;
    gemm_t<128, 128><<<dim3(p.gx * p.gy * kE * 4), 512, 0, stream>>>(p);
  }
  // ---- reduce: out = sum(part) + b2[eid] + lnca ----
  ffn2_reduce<<<kTok, 256, 0, stream>>>(part_f, lnca_f, b2, eid_d, out);
}

// Round 11
// 621.406 us; speedup vs baseline: 1.1729x; 1.0059x over previous
//
#include <hip/hip_runtime.h>
#include <stdint.h>
#include <stddef.h>

typedef _Float16 f16;
typedef _Float16 half8 __attribute__((ext_vector_type(8)));
typedef float f32x4 __attribute__((ext_vector_type(4)));

constexpr int kB = 4, kSQ = 512, kSK = 1024, kH = 1024, kHeads = 16, kE = 8, kDFF = 4096;
constexpr int kTok = kB * kSQ;  // 2048 gen tokens

// async global->LDS, 16B per lane; LDS dest must be wave-uniform base + lane*16
__device__ __forceinline__ void g2l16(const f16* g, f16* l) {
  __builtin_amdgcn_global_load_lds((const __attribute__((address_space(1))) uint32_t*)g,
                                   (__attribute__((address_space(3))) uint32_t*)l, 16, 0, 0);
}

// bijective XCD chunk swizzle (T1): physical round-robin -> contiguous logical
// chunk per XCD. Requires nwg % 8 == 0 (all our grids are).
__device__ __forceinline__ int xcd_swz(int phys, int nwg) {
  return (phys & 7) * (nwg >> 3) + (phys >> 3);
}

// four 1024x1024 weight transposes in one launch (z selects matrix)
struct Tr4P { const float* s0; const float* s1; const float* s2; const float* s3;
              f16* d0; f16* d1; f16* d2; f16* d3; };
__global__ __launch_bounds__(256) void tr_f2h4(Tr4P tp) {
  __shared__ float t[32][33];
  int z = blockIdx.z;
  const float* src = z == 0 ? tp.s0 : z == 1 ? tp.s1 : z == 2 ? tp.s2 : tp.s3;
  f16* dst = z == 0 ? tp.d0 : z == 1 ? tp.d1 : z == 2 ? tp.d2 : tp.d3;
  int r0 = blockIdx.y * 32, c0 = blockIdx.x * 32;
  int tr = threadIdx.x >> 3, tc = (threadIdx.x & 7) << 2;
  float4 v = *(const float4*)(src + (long)(r0 + tr) * kH + c0 + tc);
  t[tr][tc] = v.x; t[tr][tc + 1] = v.y; t[tr][tc + 2] = v.z; t[tr][tc + 3] = v.w;
  __syncthreads();
  union { f16 h[4]; uint2 u; } o;
  o.h[0] = (f16)t[tc + 0][tr]; o.h[1] = (f16)t[tc + 1][tr];
  o.h[2] = (f16)t[tc + 2][tr]; o.h[3] = (f16)t[tc + 3][tr];
  *(uint2*)(dst + (long)(c0 + tr) * kH + r0 + tc) = o.u;
}

// w1 (z<8: [1024][4096]) and w2 (z>=8: [4096][1024]) transposes, one launch.
// grid (128, 32, 16); for w2 the 4096 tiles are re-flattened to 32x128.
__global__ __launch_bounds__(256) void tr_f2h_w12(const float* __restrict__ w1,
                                                  const float* __restrict__ w2,
                                                  f16* __restrict__ w1_t,
                                                  f16* __restrict__ w2_t) {
  __shared__ float t[32][33];
  int z = blockIdx.z;
  const float* src;
  f16* dst;
  int R, C, cx, ry;
  if (z < 8) {
    src = w1 + (long)z * kH * kDFF; dst = w1_t + (long)z * kH * kDFF;
    R = kH; C = kDFF; cx = blockIdx.x; ry = blockIdx.y;                 // 128 x 32
  } else {
    src = w2 + (long)(z - 8) * kDFF * kH; dst = w2_t + (long)(z - 8) * kDFF * kH;
    R = kDFF; C = kH;
    int ft = blockIdx.y * 128 + blockIdx.x;                              // 0..4095
    cx = ft & 31; ry = ft >> 5;                                          // 32 x 128
  }
  int r0 = ry * 32, c0 = cx * 32;
  int tr = threadIdx.x >> 3, tc = (threadIdx.x & 7) << 2;
  float4 v = *(const float4*)(src + (long)(r0 + tr) * C + c0 + tc);
  t[tr][tc] = v.x; t[tr][tc + 1] = v.y; t[tr][tc + 2] = v.z; t[tr][tc + 3] = v.w;
  __syncthreads();
  union { f16 h[4]; uint2 u; } o;
  o.h[0] = (f16)t[tc + 0][tr]; o.h[1] = (f16)t[tc + 1][tr];
  o.h[2] = (f16)t[tc + 2][tr]; o.h[3] = (f16)t[tc + 3][tr];
  *(uint2*)(dst + (long)(c0 + tr) * R + r0 + tc) = o.u;
}

// ---------------- LayerNorm over H=1024, one block (256 thr) per row --------
// Merged dual-input form: rows [0,rows0) from x0->o0, rest from x1->o1 (fp16 only).
__global__ __launch_bounds__(256) void ln2_kernel(const float* __restrict__ x0,
                                                  const float* __restrict__ x1,
                                                  const float* __restrict__ g,
                                                  const float* __restrict__ b,
                                                  f16* __restrict__ o0,
                                                  f16* __restrict__ o1, int rows0) {
  int row = blockIdx.x;
  const float* xr;
  f16* orow;
  if (row < rows0) { xr = x0 + (long)row * kH; orow = o0 + (long)row * kH; }
  else { int r2 = row - rows0; xr = x1 + (long)r2 * kH; orow = o1 + (long)r2 * kH; }
  int tid = threadIdx.x;
  float4 v = *(const float4*)(xr + tid * 4);
  float s = v.x + v.y + v.z + v.w;
  float s2 = v.x * v.x + v.y * v.y + v.z * v.z + v.w * v.w;
  __shared__ float red[8];
  for (int o = 32; o; o >>= 1) { s += __shfl_down(s, o); s2 += __shfl_down(s2, o); }
  int wv = tid >> 6, lane = tid & 63;
  if (lane == 0) { red[wv] = s; red[4 + wv] = s2; }
  __syncthreads();
  if (tid == 0) {
    red[0] = red[0] + red[1] + red[2] + red[3];
    red[4] = red[4] + red[5] + red[6] + red[7];
  }
  __syncthreads();
  float mean = red[0] * (1.0f / kH);
  float var = red[4] * (1.0f / kH) - mean * mean;
  float rs = rsqrtf(var + 1e-6f);
  float4 gv = *(const float4*)(g + tid * 4);
  float4 bv = *(const float4*)(b + tid * 4);
  union { f16 h[4]; uint2 u; } o;
  o.h[0] = (f16)((v.x - mean) * rs * gv.x + bv.x);
  o.h[1] = (f16)((v.y - mean) * rs * gv.y + bv.y);
  o.h[2] = (f16)((v.z - mean) * rs * gv.z + bv.z);
  o.h[3] = (f16)((v.w - mean) * rs * gv.w + bv.w);
  *(uint2*)(orow + tid * 4) = o.u;
}

// Single-input LN with fp32+fp16 outputs; also zeroes zc[0..7] (router cursors)
// from block 0 -- stream order guarantees visibility before router launch.
__global__ __launch_bounds__(256) void ln_kernel(const float* __restrict__ x,
                                                 const float* __restrict__ g,
                                                 const float* __restrict__ b,
                                                 f16* __restrict__ oh, float* __restrict__ of,
                                                 int* __restrict__ zc) {
  int row = blockIdx.x;
  int tid = threadIdx.x;
  if (zc && row == 0 && tid < kE) zc[tid] = 0;
  const float* xr = x + (long)row * kH;
  float4 v = *(const float4*)(xr + tid * 4);
  float s = v.x + v.y + v.z + v.w;
  float s2 = v.x * v.x + v.y * v.y + v.z * v.z + v.w * v.w;
  __shared__ float red[8];
  for (int o = 32; o; o >>= 1) { s += __shfl_down(s, o); s2 += __shfl_down(s2, o); }
  int wv = tid >> 6, lane = tid & 63;
  if (lane == 0) { red[wv] = s; red[4 + wv] = s2; }
  __syncthreads();
  if (tid == 0) {
    red[0] = red[0] + red[1] + red[2] + red[3];
    red[4] = red[4] + red[5] + red[6] + red[7];
  }
  __syncthreads();
  float mean = red[0] * (1.0f / kH);
  float var = red[4] * (1.0f / kH) - mean * mean;
  float rs = rsqrtf(var + 1e-6f);
  float4 gv = *(const float4*)(g + tid * 4);
  float4 bv = *(const float4*)(b + tid * 4);
  float y0 = (v.x - mean) * rs * gv.x + bv.x;
  float y1 = (v.y - mean) * rs * gv.y + bv.y;
  float y2 = (v.z - mean) * rs * gv.z + bv.z;
  float y3 = (v.w - mean) * rs * gv.w + bv.w;
  long base = (long)row * kH + tid * 4;
  union { f16 h[4]; uint2 u; } o;
  o.h[0] = (f16)y0; o.h[1] = (f16)y1; o.h[2] = (f16)y2; o.h[3] = (f16)y3;
  *(uint2*)(oh + base) = o.u;
  float4 o4 = {y0, y1, y2, y3};
  *(float4*)(of + base) = o4;
}

// ---------------- router: fp32 logits, first-index argmax, bucket tokens ----
__global__ __launch_bounds__(64) void router_kernel(const float* __restrict__ ca,
                                                    const float* __restrict__ gw,
                                                    const float* __restrict__ gb,
                                                    int* __restrict__ cursors,
                                                    int* __restrict__ list,
                                                    int* __restrict__ eid) {
  int t = blockIdx.x;
  int lane = threadIdx.x;
  const float* x = ca + (long)t * kH;
  float acc[kE];
#pragma unroll
  for (int e = 0; e < kE; e++) acc[e] = 0.0f;
  for (int h = lane; h < kH; h += 64) {
    float xv = x[h];
    const float* gr = gw + (long)h * kE;
#pragma unroll
    for (int e = 0; e < kE; e++) acc[e] += xv * gr[e];
  }
#pragma unroll
  for (int e = 0; e < kE; e++)
    for (int o = 32; o; o >>= 1) acc[e] += __shfl_down(acc[e], o);
  if (lane == 0) {
    int best = 0;
    float bv = acc[0] + gb[0];
    for (int e = 1; e < kE; e++) {
      float v = acc[e] + gb[e];
      if (v > bv) { bv = v; best = e; }  // strict > == first-index argmax
    }
    int slot = atomicAdd(&cursors[best], 1);
    list[best * kTok + slot] = t;
    eid[t] = best;
  }
}

// ---------------- FFN2 reduce: out = sum(part[0..3]) + b2[eid] + lnca --------
__global__ __launch_bounds__(256) void ffn2_reduce(const float* __restrict__ part,
                                                   const float* __restrict__ lnca,
                                                   const float* __restrict__ b2,
                                                   const int* __restrict__ eid,
                                                   float* __restrict__ out) {
  int t = blockIdx.x;
  int i = threadIdx.x * 4;
  int e = eid[t];
  long idx = (long)t * kH + i;
  float4 p0 = *(const float4*)(part + idx);
  float4 p1 = *(const float4*)(part + (long)kTok * kH + idx);
  float4 p2 = *(const float4*)(part + 2L * kTok * kH + idx);
  float4 p3 = *(const float4*)(part + 3L * kTok * kH + idx);
  float4 r  = *(const float4*)(lnca + idx);
  float4 bb = *(const float4*)(b2 + (long)e * kH + i);
  float4 o = {p0.x + p1.x + p2.x + p3.x + r.x + bb.x,
              p0.y + p1.y + p2.y + p3.y + r.y + bb.y,
              p0.z + p1.z + p2.z + p3.z + r.z + bb.z,
              p0.w + p1.w + p2.w + p3.w + r.w + bb.w};
  *(float4*)(out + idx) = o;
}

// ---------------- fused flash attention (2-phase dbuf K/V staging) ----------
// K/V staged row-contiguous (8 lanes per 128B row), XOR-swizzled source+read.
__global__ __launch_bounds__(256) void flash_kernel(const f16* __restrict__ q,
                                                    const f16* __restrict__ k,
                                                    const f16* __restrict__ v_t,
                                                    const float* __restrict__ mask,
                                                    f16* __restrict__ ctx) {
  __shared__ f16 Ks0[64 * 64], Ks1[64 * 64];
  __shared__ f16 Vs0[64 * 64], Vs1[64 * 64];
  __shared__ f16 Ps[4][16][72];  // pitch 72 (144B) breaks write conflicts
  int l = xcd_swz(blockIdx.x, gridDim.x);
  int qt = l & 7;          // kSQ/64 = 8 q-tiles, fastest
  int bh = l >> 3;
  int b = bh >> 4;
  int ho = (bh & 15) * 64;
  int tid = threadIdx.x, lane = tid & 63, wave = tid >> 6;
  int quad = lane >> 4, lo = lane & 15;

  long qg = ((long)b * kSQ + qt * 64 + wave * 16 + lo) * kH + ho;
  half8 aq0 = *(const half8*)(q + qg + quad * 8);
  half8 aq1 = *(const half8*)(q + qg + 32 + quad * 8);

  int srow = tid >> 3;                       // 0..31 within group
  int soct = (tid & 7) ^ (srow & 7);         // swizzled k/sk octet
  const f16* ksrc[2];
  const f16* vsrc[2];
#pragma unroll
  for (int s = 0; s < 2; s++) {
    int r = s * 32 + srow;
    ksrc[s] = k + ((long)b * kSK + r) * kH + ho + soct * 8;       // row = key
    vsrc[s] = v_t + ((long)bh * 64 + r) * kSK + soct * 8;         // row = d
  }
  const float* maskp = mask + ((long)b * kSQ + qt * 64 + wave * 16 + quad * 4) * kSK;

  float m_s[4] = {-1e30f, -1e30f, -1e30f, -1e30f};
  float l_s[4] = {0.f, 0.f, 0.f, 0.f};
  f32x4 O[4] = {};

  auto stageKV = [&](f16* Kd, f16* Vd, int sk0) {
#pragma unroll
    for (int s = 0; s < 2; s++) g2l16(ksrc[s] + (long)sk0 * kH, &Kd[(s * 256 + tid) * 8]);
#pragma unroll
    for (int s = 0; s < 2; s++) g2l16(vsrc[s] + sk0, &Vd[(s * 256 + tid) * 8]);
  };
  auto computeT = [&](const f16* Kc, const f16* Vc, int kt) {
    int sk0 = kt * 64;
    f32x4 sf[4] = {};
#pragma unroll
    for (int nt = 0; nt < 4; nt++) {
      int key = nt * 16 + lo;
      half8 bk0 = *(const half8*)&Kc[key * 64 + (((0 * 4 + quad)) ^ (key & 7)) * 8];
      half8 bk1 = *(const half8*)&Kc[key * 64 + (((1 * 4 + quad)) ^ (key & 7)) * 8];
      sf[nt] = __builtin_amdgcn_mfma_f32_16x16x32_f16(aq0, bk0, sf[nt], 0, 0, 0);
      sf[nt] = __builtin_amdgcn_mfma_f32_16x16x32_f16(aq1, bk1, sf[nt], 0, 0, 0);
    }
#pragma unroll
    for (int r = 0; r < 4; r++)
#pragma unroll
      for (int nt = 0; nt < 4; nt++)
        sf[nt][r] += maskp[(long)r * kSK + sk0 + nt * 16 + lo];
#pragma unroll
    for (int r = 0; r < 4; r++) {
      float mx = fmaxf(fmaxf(sf[0][r], sf[1][r]), fmaxf(sf[2][r], sf[3][r]));
      mx = fmaxf(mx, __shfl_xor(mx, 1));
      mx = fmaxf(mx, __shfl_xor(mx, 2));
      mx = fmaxf(mx, __shfl_xor(mx, 4));
      mx = fmaxf(mx, __shfl_xor(mx, 8));
      float m_new = fmaxf(m_s[r], mx);
      float alpha = __expf(m_s[r] - m_new);
      m_s[r] = m_new;
      float p0 = __expf(sf[0][r] - m_new), p1 = __expf(sf[1][r] - m_new);
      float p2 = __expf(sf[2][r] - m_new), p3 = __expf(sf[3][r] - m_new);
      float rs = p0 + p1 + p2 + p3;
      rs += __shfl_xor(rs, 1);
      rs += __shfl_xor(rs, 2);
      rs += __shfl_xor(rs, 4);
      rs += __shfl_xor(rs, 8);
      l_s[r] = l_s[r] * alpha + rs;
#pragma unroll
      for (int nt = 0; nt < 4; nt++) O[nt][r] *= alpha;
      Ps[wave][quad * 4 + r][0 * 16 + lo] = (f16)p0;
      Ps[wave][quad * 4 + r][1 * 16 + lo] = (f16)p1;
      Ps[wave][quad * 4 + r][2 * 16 + lo] = (f16)p2;
      Ps[wave][quad * 4 + r][3 * 16 + lo] = (f16)p3;
    }
    half8 ap0 = *(const half8*)&Ps[wave][lo][quad * 8];
    half8 ap1 = *(const half8*)&Ps[wave][lo][32 + quad * 8];
#pragma unroll
    for (int nt = 0; nt < 4; nt++) {
      int d = nt * 16 + lo;
      half8 bv0 = *(const half8*)&Vc[d * 64 + (((0 * 4 + quad)) ^ (d & 7)) * 8];
      half8 bv1 = *(const half8*)&Vc[d * 64 + (((1 * 4 + quad)) ^ (d & 7)) * 8];
      O[nt] = __builtin_amdgcn_mfma_f32_16x16x32_f16(ap0, bv0, O[nt], 0, 0, 0);
      O[nt] = __builtin_amdgcn_mfma_f32_16x16x32_f16(ap1, bv1, O[nt], 0, 0, 0);
    }
  };

  constexpr int NT = kSK / 64;  // 16 (even)
  stageKV(Ks0, Vs0, 0);
  __syncthreads();
  for (int kt = 0; kt < NT; kt += 2) {
    if (kt + 1 < NT) stageKV(Ks1, Vs1, (kt + 1) * 64);
    computeT(Ks0, Vs0, kt);
    __syncthreads();
    if (kt + 1 < NT) {
      if (kt + 2 < NT) stageKV(Ks0, Vs0, (kt + 2) * 64);
      computeT(Ks1, Vs1, kt + 1);
      __syncthreads();
    }
  }
#pragma unroll
  for (int r = 0; r < 4; r++) {
    float inv = 1.0f / l_s[r];
    long row = (long)b * kSQ + qt * 64 + wave * 16 + quad * 4 + r;
#pragma unroll
    for (int nt = 0; nt < 4; nt++)
      ctx[row * kH + ho + nt * 16 + lo] = (f16)(O[nt][r] * inv);
  }
}

// ---------------- tiled fp16 MFMA GEMM, BK=64, 512 thr / 8 waves (2x4) ------
// C[M,N] = epilogue(A[M,K] @ B[N,K]^T); B is [N][K] k-contiguous.
// 8 waves raise waves/SIMD to 4 under grid-limited working sets.
// Per-wave tile (BM/2)x(BN/4); FM=BM/32, FN=BN/64 16x16 frags.
// Row-contiguous staging (8 lanes per 128B row), XOR-swizzled source + reads.
// 2-phase dbuf; 1D grid + XCD chunk swizzle.
struct GemmP {
  const f16* A; long a_row, a_z1, a_z2;
  const f16* Bm; long b_nstr, b_z1, b_z2;
  float* Cf; f16* Ch; long c_row, c_z1, c_z2, c_split; int c_tr;
  const float* bias; long bias_z;
  const float* res; long res_row, res_z1, res_z2;
  float alpha; int gelu; int ksplit;
  int M, N, K, zdiv;
  int gx, gy;  // logical grid dims (z = rest)
  const int* glist; const int* cnt;  // expert-gather mode: z = expert
};

template <int BM, int BN>
__device__ __forceinline__ void gemm_body(const GemmP& p, int bx, int by, int bz,
                                          f16* A0, f16* A1, f16* B0, f16* B1) {
  constexpr int FM = BM / 32, FN = BN / 64;
  constexpr int SA = BM / 64, SB = BN / 64;  // staging iters (512 thr)
  int z = bz;
  int kb = 0, kEnd = p.K, ks = 0;
  if (p.ksplit > 1) {
    int kc = p.K / p.ksplit;
    ks = z % p.ksplit;
    kb = ks * kc;
    kEnd = kb + kc;
    z /= p.ksplit;
  }
  long aoff = 0, boff = 0, coff = 0, roff = 0, biasoff = 0;
  const int* gl = nullptr;
  int Meff = p.M;
  if (p.glist) {
    Meff = p.cnt[z];
    gl = p.glist + (long)z * kTok;
    boff = (long)z * p.b_z2;
    biasoff = (long)z * p.bias_z;
  } else {
    int z1 = z / p.zdiv, z2 = z % p.zdiv;
    aoff = (long)z1 * p.a_z1 + (long)z2 * p.a_z2;
    boff = (long)z1 * p.b_z1 + (long)z2 * p.b_z2;
    coff = (long)z1 * p.c_z1 + (long)z2 * p.c_z2;
    roff = (long)z1 * p.res_z1 + (long)z2 * p.res_z2;
  }
  coff += (long)ks * p.c_split;
  int m0 = by * BM;
  if (m0 >= Meff) return;
  int n0 = bx * BN;
  int tid = threadIdx.x, lane = tid & 63, wave = tid >> 6;   // wave 0..7
  int wm = (wave & 1) * (BM / 2), wn = (wave >> 1) * (BN / 4);
  int q = lane >> 4, lo = lane & 15;

  // row-contiguous staging: chunk c = s*512+tid -> row = s*64 + (tid>>3),
  // source k-octet = (tid&7) ^ (row&7); LDS dest linear -> [row][slot].
  int srow = tid >> 3;
  int soct = (tid & 7) ^ (srow & 7);
  const f16* asrc[SA];
  const f16* bsrc[SB];
#pragma unroll
  for (int s = 0; s < SA; s++) {
    int row = m0 + s * 64 + srow;
    if (gl) row = gl[row < Meff ? row : Meff - 1];  // clamp: garbage rows never stored
    asrc[s] = p.A + aoff + (long)row * p.a_row + soct * 8;
  }
#pragma unroll
  for (int s = 0; s < SB; s++)
    bsrc[s] = p.Bm + boff + (long)(n0 + s * 64 + srow) * p.b_nstr + soct * 8;

  f32x4 acc[FM][FN] = {};

  auto stage = [&](f16* Ad, f16* Bd, int k0) {
#pragma unroll
    for (int s = 0; s < SA; s++) g2l16(asrc[s] + k0, &Ad[(s * 512 + tid) * 8]);
#pragma unroll
    for (int s = 0; s < SB; s++) g2l16(bsrc[s] + k0, &Bd[(s * 512 + tid) * 8]);
  };
  auto compute = [&](const f16* As, const f16* Bs) {
    half8 af[2][FM], bf[2][FN];
#pragma unroll
    for (int kk = 0; kk < 2; kk++) {
#pragma unroll
      for (int i = 0; i < FM; i++) {
        int r = wm + i * 16 + lo;
        af[kk][i] = *(const half8*)&As[r * 64 + ((kk * 4 + q) ^ (r & 7)) * 8];
      }
#pragma unroll
      for (int j = 0; j < FN; j++) {
        int n = wn + j * 16 + lo;
        bf[kk][j] = *(const half8*)&Bs[n * 64 + ((kk * 4 + q) ^ (n & 7)) * 8];
      }
    }
#pragma unroll
    for (int kk = 0; kk < 2; kk++)
#pragma unroll
      for (int i = 0; i < FM; i++)
#pragma unroll
        for (int j = 0; j < FN; j++)
          acc[i][j] = __builtin_amdgcn_mfma_f32_16x16x32_f16(af[kk][i], bf[kk][j], acc[i][j], 0, 0, 0);
  };

  // 2-phase pipeline: stage(next) issued before compute(cur); one barrier per K-step.
  stage(A0, B0, kb);
  __syncthreads();
  for (int k0 = kb; k0 < kEnd; k0 += 128) {
    if (k0 + 64 < kEnd) stage(A1, B1, k0 + 64);
    compute(A0, B0);
    __syncthreads();
    if (k0 + 64 < kEnd) {
      if (k0 + 128 < kEnd) stage(A0, B0, k0 + 128);
      compute(A1, B1);
      __syncthreads();
    }
  }

#pragma unroll
  for (int i = 0; i < FM; i++) {
#pragma unroll
    for (int j = 0; j < FN; j++) {
      int col = n0 + wn + j * 16 + lo;
      if (p.c_tr) {  // transposed f16 store: 4 consecutive rows -> one 8B store
        int row0 = m0 + wm + i * 16 + q * 4;
        union { f16 h[4]; uint2 u; } o;
#pragma unroll
        for (int r = 0; r < 4; r++) {
          float v = acc[i][j][r];
          if (p.bias) v += p.bias[biasoff + col];
          v *= p.alpha;
          o.h[r] = (f16)v;
        }
        *(uint2*)&p.Ch[coff + (long)col * p.c_row + row0] = o.u;
      } else {
#pragma unroll
        for (int r = 0; r < 4; r++) {
          int row = m0 + wm + i * 16 + q * 4 + r;
          if (row < Meff) {
            long rr = gl ? (long)gl[row] : (long)row;
            float v = acc[i][j][r];
            if (p.bias) v += p.bias[biasoff + col];
            v *= p.alpha;
            if (p.res) v += p.res[roff + rr * p.res_row + col];
            if (p.gelu) v = 0.5f * v * (1.0f + erff(v * 0.70710678118654752f));
            long ci = coff + rr * p.c_row + col;
            if (p.Cf) p.Cf[ci] = v;
            else p.Ch[ci] = (f16)v;
          }
        }
      }
    }
  }
}

template <int BM, int BN>
__global__ __launch_bounds__(512) void gemm_t(GemmP p) {
  __shared__ f16 A0[BM * 64], A1[BM * 64], B0[BN * 64], B1[BN * 64];
  int l = xcd_swz(blockIdx.x, gridDim.x);
  int bx = l % p.gx;
  int r = l / p.gx;
  int by = r % p.gy;
  int bz = r / p.gy;
  gemm_body<BM, BN>(p, bx, by, bz, A0, A1, B0, B1);
}

// fused Q/K/V projections: one flat grid, block ranges per sub-GEMM (128x128 tiles)
struct Multi3P {
  GemmP g0, g1, g2;
  int n0, n1;
  int gx0, gy0, gx1, gy1, gx2, gy2;
};

__global__ __launch_bounds__(512) void gemm_qkv(Multi3P mp) {
  __shared__ f16 A0[128 * 64], A1[128 * 64], B0[128 * 64], B1[128 * 64];
  int fb = xcd_swz(blockIdx.x, gridDim.x);
  if (fb < mp.n0) {
    gemm_body<128, 128>(mp.g0, fb % mp.gx0, (fb / mp.gx0) % mp.gy0, fb / (mp.gx0 * mp.gy0),
                        A0, A1, B0, B1);
    return;
  }
  fb -= mp.n0;
  if (fb < mp.n1) {
    gemm_body<128, 128>(mp.g1, fb % mp.gx1, (fb / mp.gx1) % mp.gy1, fb / (mp.gx1 * mp.gy1),
                        A0, A1, B0, B1);
    return;
  }
  fb -= mp.n1;
  gemm_body<128, 128>(mp.g2, fb % mp.gx2, (fb / mp.gx2) % mp.gy2, fb / (mp.gx2 * mp.gy2),
                      A0, A1, B0, B1);
}

extern "C" void kernel_launch(void* const* d_in, const int* in_sizes, int n_in,
                              void* d_out, int out_size, void* d_ws, size_t ws_size,
                              hipStream_t stream) {
  const float* concated = (const float*)d_in[0];
  const float* gen      = (const float*)d_in[1];
  const float* mask     = (const float*)d_in[2];
  const float* ln_g     = (const float*)d_in[3];
  const float* ln_b     = (const float*)d_in[4];
  const float* wq = (const float*)d_in[5];  const float* bq = (const float*)d_in[6];
  const float* wk = (const float*)d_in[7];  const float* bk = (const float*)d_in[8];
  const float* wv = (const float*)d_in[9];  const float* bv = (const float*)d_in[10];
  const float* wo = (const float*)d_in[11]; const float* bo = (const float*)d_in[12];
  const float* gw = (const float*)d_in[13]; const float* gb = (const float*)d_in[14];
  const float* w1 = (const float*)d_in[15]; const float* b1 = (const float*)d_in[16];
  const float* w2 = (const float*)d_in[17]; const float* b2 = (const float*)d_in[18];
  float* out = (float*)d_out;

  size_t off = 0;
  auto alloc = [&](size_t bytes) -> void* {
    void* p = (char*)d_ws + off;
    off += (bytes + 255) & ~(size_t)255;
    return p;
  };
  f16* wq_t  = (f16*)alloc((size_t)kH * kH * 2);       // [N][K]
  f16* wk_t  = (f16*)alloc((size_t)kH * kH * 2);
  f16* wv_t  = (f16*)alloc((size_t)kH * kH * 2);
  f16* wo_t  = (f16*)alloc((size_t)kH * kH * 2);
  f16* w1_t  = (f16*)alloc((size_t)kE * kH * kDFF * 2);  // [E][DFF][H]
  f16* w2_t  = (f16*)alloc((size_t)kE * kDFF * kH * 2);  // [E][H][DFF]
  f16* lnc_h = (f16*)alloc((size_t)kB * kSK * kH * 2);
  f16* lng_h = (f16*)alloc((size_t)kTok * kH * 2);
  f16* q_h   = (f16*)alloc((size_t)kTok * kH * 2);
  f16* k_h   = (f16*)alloc((size_t)kB * kSK * kH * 2);
  f16* v_t   = (f16*)alloc((size_t)kB * kSK * kH * 2);   // [b][h][d][sk]
  f16* ctx_h = (f16*)alloc((size_t)kTok * kH * 2);
  float* ca_f   = (float*)alloc((size_t)kTok * kH * 4);
  float* lnca_f = (float*)alloc((size_t)kTok * kH * 4);
  f16* lnca_h   = (f16*)alloc((size_t)kTok * kH * 2);
  f16* h1_h     = (f16*)alloc((size_t)kTok * kDFF * 2);
  float* part_f = (float*)alloc((size_t)4 * kTok * kH * 4);
  int* cnt_d    = (int*)alloc(kE * 4);
  int* list_d   = (int*)alloc((size_t)kE * kTok * 4);
  int* eid_d    = (int*)alloc((size_t)kTok * 4);

  // ---- weight transpose-convert fp32 [K][N] -> fp16 [N][K] (2 launches) ----
  {
    Tr4P tp{wq, wk, wv, wo, wq_t, wk_t, wv_t, wo_t};
    tr_f2h4<<<dim3(32, 32, 4), 256, 0, stream>>>(tp);
  }
  tr_f2h_w12<<<dim3(128, 32, 16), 256, 0, stream>>>(w1, w2, w1_t, w2_t);

  // ---- LayerNorms of both inputs (one launch) ----
  ln2_kernel<<<kB * kSK + kTok, 256, 0, stream>>>(concated, gen, ln_g, ln_b,
                                                  lnc_h, lng_h, kB * kSK);

  // ---- fused Q/K/V projections (one launch, 640 blocks at 128x128, 8 waves) ----
  {
    Multi3P mp{};
    GemmP& pq = mp.g0;
    pq.A = lng_h; pq.a_row = kH; pq.Bm = wq_t; pq.b_nstr = kH;
    pq.Ch = q_h; pq.c_row = kH; pq.bias = bq; pq.alpha = 0.125f;
    pq.M = kTok; pq.N = kH; pq.K = kH; pq.zdiv = 1;
    GemmP& pk = mp.g1;
    pk.A = lnc_h; pk.a_row = kH; pk.Bm = wk_t; pk.b_nstr = kH;
    pk.Ch = k_h; pk.c_row = kH; pk.bias = bk; pk.alpha = 1.0f;
    pk.M = kB * kSK; pk.N = kH; pk.K = kH; pk.zdiv = 1;
    GemmP& pv = mp.g2;
    pv.A = lnc_h; pv.a_row = kH; pv.a_z1 = (long)kSK * kH;
    pv.Bm = wv_t; pv.b_nstr = kH;
    pv.Ch = v_t; pv.c_row = kSK; pv.c_z1 = (long)kH * kSK; pv.c_tr = 1;
    pv.bias = bv; pv.alpha = 1.0f;
    pv.M = kSK; pv.N = kH; pv.K = kH; pv.zdiv = 1;
    mp.gx0 = kH / 128; mp.gy0 = kTok / 128;        mp.n0 = mp.gx0 * mp.gy0;       // 128
    mp.gx1 = kH / 128; mp.gy1 = (kB * kSK) / 128;  mp.n1 = mp.gx1 * mp.gy1;       // 256
    mp.gx2 = kH / 128; mp.gy2 = kSK / 128;                                         // x8, z=4
    int ntot = mp.n0 + mp.n1 + mp.gx2 * mp.gy2 * kB;                               // 640
    gemm_qkv<<<dim3(ntot), 512, 0, stream>>>(mp);
  }
  // ---- fused flash attention -> ctx_h (1D grid, XCD swizzle) ----
  flash_kernel<<<dim3((kSQ / 64) * kB * kHeads), 256, 0, stream>>>(q_h, k_h, v_t, mask, ctx_h);
  // ---- ca_out = ctx @ wo^T + bo + gen (fp32 out) ----
  {
    GemmP p{}; p.A = ctx_h; p.a_row = kH;
    p.Bm = wo_t; p.b_nstr = kH;
    p.Cf = ca_f; p.c_row = kH; p.bias = bo;
    p.res = gen; p.res_row = kH;
    p.alpha = 1.0f; p.M = kTok; p.N = kH; p.K = kH; p.zdiv = 1;
    p.gx = kH / 64; p.gy = kTok / 64;
    gemm_t<64, 64><<<dim3(p.gx * p.gy), 512, 0, stream>>>(p);
  }
  // ---- ln_ca (fp32 + fp16) + zero router cursors ----
  ln_kernel<<<kTok, 256, 0, stream>>>(ca_f, ln_g, ln_b, lnca_h, lnca_f, cnt_d);
  // ---- router + expert bucketing ----
  router_kernel<<<kTok, 64, 0, stream>>>(ca_f, gw, gb, cnt_d, list_d, eid_d);
  // ---- FFN1: h1 = gelu(ln_ca @ w1[e] + b1[e]) ; 128x128 tile, 8 waves ----
  {
    GemmP p{}; p.A = lnca_h; p.a_row = kH;
    p.Bm = w1_t; p.b_nstr = kH; p.b_z2 = (long)kH * kDFF;
    p.Ch = h1_h; p.c_row = kDFF; p.bias = b1; p.bias_z = kDFF;
    p.alpha = 1.0f; p.gelu = 1; p.M = kTok; p.N = kDFF; p.K = kH; p.zdiv = 1;
    p.glist = list_d; p.cnt = cnt_d;
    p.gx = kDFF / 128; p.gy = kTok / 128;
    gemm_t<128, 128><<<dim3(p.gx * p.gy * kE), 512, 0, stream>>>(p);
  }
  // ---- FFN2: part[s] = h1 @ w2[e] (split-K x4, fp32 partials, no atomics) ----
  {
    GemmP p{}; p.A = h1_h; p.a_row = kDFF;
    p.Bm = w2_t; p.b_nstr = kDFF; p.b_z2 = (long)kDFF * kH;
    p.Cf = part_f; p.c_row = kH; p.c_split = (long)kTok * kH;
    p.alpha = 1.0f; p.ksplit = 4;
    p.M = kTok; p.N = kH; p.K = kDFF; p.zdiv = 1;
    p.glist = list_d; p.cnt = cnt_d;
    p.gx = kH / 128; p.gy = kTok / 128;
    gemm_t<128, 128><<<dim3(p.gx * p.gy * kE * 4), 512, 0, stream>>>(p);
  }
  // ---- reduce: out = sum(part) + b2[eid] + lnca ----
  ffn2_reduce<<<kTok, 256, 0, stream>>>(part_f, lnca_f, b2, eid_d, out);
}

// Round 12
// 620.145 us; speedup vs baseline: 1.1753x; 1.0020x over previous
//
#include <hip/hip_runtime.h>
#include <stdint.h>
#include <stddef.h>

typedef _Float16 f16;
typedef _Float16 half8 __attribute__((ext_vector_type(8)));
typedef float f32x4 __attribute__((ext_vector_type(4)));

constexpr int kB = 4, kSQ = 512, kSK = 1024, kH = 1024, kHeads = 16, kE = 8, kDFF = 4096;
constexpr int kTok = kB * kSQ;  // 2048 gen tokens

// async global->LDS, 16B per lane; LDS dest must be wave-uniform base + lane*16
__device__ __forceinline__ void g2l16(const f16* g, f16* l) {
  __builtin_amdgcn_global_load_lds((const __attribute__((address_space(1))) uint32_t*)g,
                                   (__attribute__((address_space(3))) uint32_t*)l, 16, 0, 0);
}

// bijective XCD chunk swizzle (T1): physical round-robin -> contiguous logical
// chunk per XCD. Requires nwg % 8 == 0 (all our grids are).
__device__ __forceinline__ int xcd_swz(int phys, int nwg) {
  return (phys & 7) * (nwg >> 3) + (phys >> 3);
}

// ---------------- all weight transposes, one launch ----------------
// 64x64 tiles; 16B loads AND 16B stores (128B contiguous per 8 lanes both sides).
// z<8: w1[e] (1024x4096); z<16: w2[e-8] (4096x1024); z==16: wq/wk/wv/wo (4x 1024^2).
struct TrAllP {
  const float* w1; const float* w2;
  const float* wq; const float* wk; const float* wv; const float* wo;
  f16* w1_t; f16* w2_t; f16* wq_t; f16* wk_t; f16* wv_t; f16* wo_t;
};
__global__ __launch_bounds__(256) void tr_all(TrAllP tp) {
  __shared__ float t[64][65];
  int z = blockIdx.z;
  int ft = blockIdx.x;
  const float* src; f16* dst; int R, C, cx, ry;
  if (z < 8) {
    src = tp.w1 + (long)z * kH * kDFF; dst = tp.w1_t + (long)z * kH * kDFF;
    R = kH; C = kDFF; cx = ft & 63; ry = ft >> 6;          // 64 x 16 tiles
  } else if (z < 16) {
    src = tp.w2 + (long)(z - 8) * kDFF * kH; dst = tp.w2_t + (long)(z - 8) * kDFF * kH;
    R = kDFF; C = kH; cx = ft & 15; ry = ft >> 4;          // 16 x 64 tiles
  } else {
    int mat = ft >> 8, t2 = ft & 255;
    src = mat == 0 ? tp.wq : mat == 1 ? tp.wk : mat == 2 ? tp.wv : tp.wo;
    dst = mat == 0 ? tp.wq_t : mat == 1 ? tp.wk_t : mat == 2 ? tp.wv_t : tp.wo_t;
    R = kH; C = kH; cx = t2 & 15; ry = t2 >> 4;            // 16 x 16 tiles
  }
  int r0 = ry * 64, c0 = cx * 64;
  int tid = threadIdx.x;
#pragma unroll
  for (int s = 0; s < 4; s++) {
    int idx = s * 256 + tid;
    int lr = idx >> 4, lc = (idx & 15) << 2;
    float4 v = *(const float4*)(src + (long)(r0 + lr) * C + c0 + lc);
    t[lr][lc] = v.x; t[lr][lc + 1] = v.y; t[lr][lc + 2] = v.z; t[lr][lc + 3] = v.w;
  }
  __syncthreads();
#pragma unroll
  for (int s = 0; s < 2; s++) {
    int idx = s * 256 + tid;
    int dr = idx >> 3, dc = (idx & 7) << 3;
    union { f16 h[8]; uint4 u; } o;
#pragma unroll
    for (int j = 0; j < 8; j++) o.h[j] = (f16)t[dc + j][dr];
    *(uint4*)(dst + (long)(c0 + dr) * R + r0 + dc) = o.u;
  }
}

// ---------------- LayerNorm over H=1024, one block (256 thr) per row --------
// Merged dual-input form: rows [0,rows0) from x0->o0, rest from x1->o1 (fp16 only).
__global__ __launch_bounds__(256) void ln2_kernel(const float* __restrict__ x0,
                                                  const float* __restrict__ x1,
                                                  const float* __restrict__ g,
                                                  const float* __restrict__ b,
                                                  f16* __restrict__ o0,
                                                  f16* __restrict__ o1, int rows0) {
  int row = blockIdx.x;
  const float* xr;
  f16* orow;
  if (row < rows0) { xr = x0 + (long)row * kH; orow = o0 + (long)row * kH; }
  else { int r2 = row - rows0; xr = x1 + (long)r2 * kH; orow = o1 + (long)r2 * kH; }
  int tid = threadIdx.x;
  float4 v = *(const float4*)(xr + tid * 4);
  float s = v.x + v.y + v.z + v.w;
  float s2 = v.x * v.x + v.y * v.y + v.z * v.z + v.w * v.w;
  __shared__ float red[8];
  for (int o = 32; o; o >>= 1) { s += __shfl_down(s, o); s2 += __shfl_down(s2, o); }
  int wv = tid >> 6, lane = tid & 63;
  if (lane == 0) { red[wv] = s; red[4 + wv] = s2; }
  __syncthreads();
  if (tid == 0) {
    red[0] = red[0] + red[1] + red[2] + red[3];
    red[4] = red[4] + red[5] + red[6] + red[7];
  }
  __syncthreads();
  float mean = red[0] * (1.0f / kH);
  float var = red[4] * (1.0f / kH) - mean * mean;
  float rs = rsqrtf(var + 1e-6f);
  float4 gv = *(const float4*)(g + tid * 4);
  float4 bv = *(const float4*)(b + tid * 4);
  union { f16 h[4]; uint2 u; } o;
  o.h[0] = (f16)((v.x - mean) * rs * gv.x + bv.x);
  o.h[1] = (f16)((v.y - mean) * rs * gv.y + bv.y);
  o.h[2] = (f16)((v.z - mean) * rs * gv.z + bv.z);
  o.h[3] = (f16)((v.w - mean) * rs * gv.w + bv.w);
  *(uint2*)(orow + tid * 4) = o.u;
}

// Single-input LN with fp32+fp16 outputs; also zeroes zc[0..7] (router cursors)
// from block 0 -- stream order guarantees visibility before router launch.
__global__ __launch_bounds__(256) void ln_kernel(const float* __restrict__ x,
                                                 const float* __restrict__ g,
                                                 const float* __restrict__ b,
                                                 f16* __restrict__ oh, float* __restrict__ of,
                                                 int* __restrict__ zc) {
  int row = blockIdx.x;
  int tid = threadIdx.x;
  if (zc && row == 0 && tid < kE) zc[tid] = 0;
  const float* xr = x + (long)row * kH;
  float4 v = *(const float4*)(xr + tid * 4);
  float s = v.x + v.y + v.z + v.w;
  float s2 = v.x * v.x + v.y * v.y + v.z * v.z + v.w * v.w;
  __shared__ float red[8];
  for (int o = 32; o; o >>= 1) { s += __shfl_down(s, o); s2 += __shfl_down(s2, o); }
  int wv = tid >> 6, lane = tid & 63;
  if (lane == 0) { red[wv] = s; red[4 + wv] = s2; }
  __syncthreads();
  if (tid == 0) {
    red[0] = red[0] + red[1] + red[2] + red[3];
    red[4] = red[4] + red[5] + red[6] + red[7];
  }
  __syncthreads();
  float mean = red[0] * (1.0f / kH);
  float var = red[4] * (1.0f / kH) - mean * mean;
  float rs = rsqrtf(var + 1e-6f);
  float4 gv = *(const float4*)(g + tid * 4);
  float4 bv = *(const float4*)(b + tid * 4);
  float y0 = (v.x - mean) * rs * gv.x + bv.x;
  float y1 = (v.y - mean) * rs * gv.y + bv.y;
  float y2 = (v.z - mean) * rs * gv.z + bv.z;
  float y3 = (v.w - mean) * rs * gv.w + bv.w;
  long base = (long)row * kH + tid * 4;
  union { f16 h[4]; uint2 u; } o;
  o.h[0] = (f16)y0; o.h[1] = (f16)y1; o.h[2] = (f16)y2; o.h[3] = (f16)y3;
  *(uint2*)(oh + base) = o.u;
  float4 o4 = {y0, y1, y2, y3};
  *(float4*)(of + base) = o4;
}

// ---------------- router: fp32 logits, first-index argmax, bucket tokens ----
__global__ __launch_bounds__(64) void router_kernel(const float* __restrict__ ca,
                                                    const float* __restrict__ gw,
                                                    const float* __restrict__ gb,
                                                    int* __restrict__ cursors,
                                                    int* __restrict__ list,
                                                    int* __restrict__ eid) {
  int t = blockIdx.x;
  int lane = threadIdx.x;
  const float* x = ca + (long)t * kH;
  float acc[kE];
#pragma unroll
  for (int e = 0; e < kE; e++) acc[e] = 0.0f;
  for (int h = lane; h < kH; h += 64) {
    float xv = x[h];
    const float* gr = gw + (long)h * kE;
#pragma unroll
    for (int e = 0; e < kE; e++) acc[e] += xv * gr[e];
  }
#pragma unroll
  for (int e = 0; e < kE; e++)
    for (int o = 32; o; o >>= 1) acc[e] += __shfl_down(acc[e], o);
  if (lane == 0) {
    int best = 0;
    float bv = acc[0] + gb[0];
    for (int e = 1; e < kE; e++) {
      float v = acc[e] + gb[e];
      if (v > bv) { bv = v; best = e; }  // strict > == first-index argmax
    }
    int slot = atomicAdd(&cursors[best], 1);
    list[best * kTok + slot] = t;
    eid[t] = best;
  }
}

// ---------------- FFN2 reduce: out = sum(part[0..3]) + b2[eid] + lnca --------
__global__ __launch_bounds__(256) void ffn2_reduce(const float* __restrict__ part,
                                                   const float* __restrict__ lnca,
                                                   const float* __restrict__ b2,
                                                   const int* __restrict__ eid,
                                                   float* __restrict__ out) {
  int t = blockIdx.x;
  int i = threadIdx.x * 4;
  int e = eid[t];
  long idx = (long)t * kH + i;
  float4 p0 = *(const float4*)(part + idx);
  float4 p1 = *(const float4*)(part + (long)kTok * kH + idx);
  float4 p2 = *(const float4*)(part + 2L * kTok * kH + idx);
  float4 p3 = *(const float4*)(part + 3L * kTok * kH + idx);
  float4 r  = *(const float4*)(lnca + idx);
  float4 bb = *(const float4*)(b2 + (long)e * kH + i);
  float4 o = {p0.x + p1.x + p2.x + p3.x + r.x + bb.x,
              p0.y + p1.y + p2.y + p3.y + r.y + bb.y,
              p0.z + p1.z + p2.z + p3.z + r.z + bb.z,
              p0.w + p1.w + p2.w + p3.w + r.w + bb.w};
  *(float4*)(out + idx) = o;
}

// ---------------- fused flash attention (2-phase dbuf K/V staging) ----------
// K/V staged row-contiguous (8 lanes per 128B row), XOR-swizzled source+read.
__global__ __launch_bounds__(256) void flash_kernel(const f16* __restrict__ q,
                                                    const f16* __restrict__ k,
                                                    const f16* __restrict__ v_t,
                                                    const float* __restrict__ mask,
                                                    f16* __restrict__ ctx) {
  __shared__ f16 Ks0[64 * 64], Ks1[64 * 64];
  __shared__ f16 Vs0[64 * 64], Vs1[64 * 64];
  __shared__ f16 Ps[4][16][72];  // pitch 72 (144B) breaks write conflicts
  int l = xcd_swz(blockIdx.x, gridDim.x);
  int qt = l & 7;          // kSQ/64 = 8 q-tiles, fastest
  int bh = l >> 3;
  int b = bh >> 4;
  int ho = (bh & 15) * 64;
  int tid = threadIdx.x, lane = tid & 63, wave = tid >> 6;
  int quad = lane >> 4, lo = lane & 15;

  long qg = ((long)b * kSQ + qt * 64 + wave * 16 + lo) * kH + ho;
  half8 aq0 = *(const half8*)(q + qg + quad * 8);
  half8 aq1 = *(const half8*)(q + qg + 32 + quad * 8);

  int srow = tid >> 3;                       // 0..31 within group
  int soct = (tid & 7) ^ (srow & 7);         // swizzled k/sk octet
  const f16* ksrc[2];
  const f16* vsrc[2];
#pragma unroll
  for (int s = 0; s < 2; s++) {
    int r = s * 32 + srow;
    ksrc[s] = k + ((long)b * kSK + r) * kH + ho + soct * 8;       // row = key
    vsrc[s] = v_t + ((long)bh * 64 + r) * kSK + soct * 8;         // row = d
  }
  const float* maskp = mask + ((long)b * kSQ + qt * 64 + wave * 16 + quad * 4) * kSK;

  float m_s[4] = {-1e30f, -1e30f, -1e30f, -1e30f};
  float l_s[4] = {0.f, 0.f, 0.f, 0.f};
  f32x4 O[4] = {};

  auto stageKV = [&](f16* Kd, f16* Vd, int sk0) {
#pragma unroll
    for (int s = 0; s < 2; s++) g2l16(ksrc[s] + (long)sk0 * kH, &Kd[(s * 256 + tid) * 8]);
#pragma unroll
    for (int s = 0; s < 2; s++) g2l16(vsrc[s] + sk0, &Vd[(s * 256 + tid) * 8]);
  };
  auto computeT = [&](const f16* Kc, const f16* Vc, int kt) {
    int sk0 = kt * 64;
    f32x4 sf[4] = {};
#pragma unroll
    for (int nt = 0; nt < 4; nt++) {
      int key = nt * 16 + lo;
      half8 bk0 = *(const half8*)&Kc[key * 64 + (((0 * 4 + quad)) ^ (key & 7)) * 8];
      half8 bk1 = *(const half8*)&Kc[key * 64 + (((1 * 4 + quad)) ^ (key & 7)) * 8];
      sf[nt] = __builtin_amdgcn_mfma_f32_16x16x32_f16(aq0, bk0, sf[nt], 0, 0, 0);
      sf[nt] = __builtin_amdgcn_mfma_f32_16x16x32_f16(aq1, bk1, sf[nt], 0, 0, 0);
    }
#pragma unroll
    for (int r = 0; r < 4; r++)
#pragma unroll
      for (int nt = 0; nt < 4; nt++)
        sf[nt][r] += maskp[(long)r * kSK + sk0 + nt * 16 + lo];
#pragma unroll
    for (int r = 0; r < 4; r++) {
      float mx = fmaxf(fmaxf(sf[0][r], sf[1][r]), fmaxf(sf[2][r], sf[3][r]));
      mx = fmaxf(mx, __shfl_xor(mx, 1));
      mx = fmaxf(mx, __shfl_xor(mx, 2));
      mx = fmaxf(mx, __shfl_xor(mx, 4));
      mx = fmaxf(mx, __shfl_xor(mx, 8));
      float m_new = fmaxf(m_s[r], mx);
      float alpha = __expf(m_s[r] - m_new);
      m_s[r] = m_new;
      float p0 = __expf(sf[0][r] - m_new), p1 = __expf(sf[1][r] - m_new);
      float p2 = __expf(sf[2][r] - m_new), p3 = __expf(sf[3][r] - m_new);
      float rs = p0 + p1 + p2 + p3;
      rs += __shfl_xor(rs, 1);
      rs += __shfl_xor(rs, 2);
      rs += __shfl_xor(rs, 4);
      rs += __shfl_xor(rs, 8);
      l_s[r] = l_s[r] * alpha + rs;
#pragma unroll
      for (int nt = 0; nt < 4; nt++) O[nt][r] *= alpha;
      Ps[wave][quad * 4 + r][0 * 16 + lo] = (f16)p0;
      Ps[wave][quad * 4 + r][1 * 16 + lo] = (f16)p1;
      Ps[wave][quad * 4 + r][2 * 16 + lo] = (f16)p2;
      Ps[wave][quad * 4 + r][3 * 16 + lo] = (f16)p3;
    }
    half8 ap0 = *(const half8*)&Ps[wave][lo][quad * 8];
    half8 ap1 = *(const half8*)&Ps[wave][lo][32 + quad * 8];
#pragma unroll
    for (int nt = 0; nt < 4; nt++) {
      int d = nt * 16 + lo;
      half8 bv0 = *(const half8*)&Vc[d * 64 + (((0 * 4 + quad)) ^ (d & 7)) * 8];
      half8 bv1 = *(const half8*)&Vc[d * 64 + (((1 * 4 + quad)) ^ (d & 7)) * 8];
      O[nt] = __builtin_amdgcn_mfma_f32_16x16x32_f16(ap0, bv0, O[nt], 0, 0, 0);
      O[nt] = __builtin_amdgcn_mfma_f32_16x16x32_f16(ap1, bv1, O[nt], 0, 0, 0);
    }
  };

  constexpr int NT = kSK / 64;  // 16 (even)
  stageKV(Ks0, Vs0, 0);
  __syncthreads();
  for (int kt = 0; kt < NT; kt += 2) {
    if (kt + 1 < NT) stageKV(Ks1, Vs1, (kt + 1) * 64);
    computeT(Ks0, Vs0, kt);
    __syncthreads();
    if (kt + 1 < NT) {
      if (kt + 2 < NT) stageKV(Ks0, Vs0, (kt + 2) * 64);
      computeT(Ks1, Vs1, kt + 1);
      __syncthreads();
    }
  }
#pragma unroll
  for (int r = 0; r < 4; r++) {
    float inv = 1.0f / l_s[r];
    long row = (long)b * kSQ + qt * 64 + wave * 16 + quad * 4 + r;
#pragma unroll
    for (int nt = 0; nt < 4; nt++)
      ctx[row * kH + ho + nt * 16 + lo] = (f16)(O[nt][r] * inv);
  }
}

// ---------------- tiled fp16 MFMA GEMM, BK=64, 512 thr / 8 waves (2x4) ------
// C[M,N] = epilogue(A[M,K] @ B[N,K]^T); B is [N][K] k-contiguous.
// 8 waves raise waves/SIMD to 4 under grid-limited working sets.
// Per-wave tile (BM/2)x(BN/4); FM=BM/32, FN=BN/64 16x16 frags.
// Row-contiguous staging (8 lanes per 128B row), XOR-swizzled source + reads.
// 2-phase dbuf; 1D grid + XCD chunk swizzle.
struct GemmP {
  const f16* A; long a_row, a_z1, a_z2;
  const f16* Bm; long b_nstr, b_z1, b_z2;
  float* Cf; f16* Ch; long c_row, c_z1, c_z2, c_split; int c_tr;
  const float* bias; long bias_z;
  const float* res; long res_row, res_z1, res_z2;
  float alpha; int gelu; int ksplit;
  int M, N, K, zdiv;
  int gx, gy;  // logical grid dims (z = rest)
  const int* glist; const int* cnt;  // expert-gather mode: z = expert
};

template <int BM, int BN>
__device__ __forceinline__ void gemm_body(const GemmP& p, int bx, int by, int bz,
                                          f16* A0, f16* A1, f16* B0, f16* B1) {
  constexpr int FM = BM / 32, FN = BN / 64;
  constexpr int SA = BM / 64, SB = BN / 64;  // staging iters (512 thr)
  int z = bz;
  int kb = 0, kEnd = p.K, ks = 0;
  if (p.ksplit > 1) {
    int kc = p.K / p.ksplit;
    ks = z % p.ksplit;
    kb = ks * kc;
    kEnd = kb + kc;
    z /= p.ksplit;
  }
  long aoff = 0, boff = 0, coff = 0, roff = 0, biasoff = 0;
  const int* gl = nullptr;
  int Meff = p.M;
  if (p.glist) {
    Meff = p.cnt[z];
    gl = p.glist + (long)z * kTok;
    boff = (long)z * p.b_z2;
    biasoff = (long)z * p.bias_z;
  } else {
    int z1 = z / p.zdiv, z2 = z % p.zdiv;
    aoff = (long)z1 * p.a_z1 + (long)z2 * p.a_z2;
    boff = (long)z1 * p.b_z1 + (long)z2 * p.b_z2;
    coff = (long)z1 * p.c_z1 + (long)z2 * p.c_z2;
    roff = (long)z1 * p.res_z1 + (long)z2 * p.res_z2;
  }
  coff += (long)ks * p.c_split;
  int m0 = by * BM;
  if (m0 >= Meff) return;
  int n0 = bx * BN;
  int tid = threadIdx.x, lane = tid & 63, wave = tid >> 6;   // wave 0..7
  int wm = (wave & 1) * (BM / 2), wn = (wave >> 1) * (BN / 4);
  int q = lane >> 4, lo = lane & 15;

  // row-contiguous staging: chunk c = s*512+tid -> row = s*64 + (tid>>3),
  // source k-octet = (tid&7) ^ (row&7); LDS dest linear -> [row][slot].
  int srow = tid >> 3;
  int soct = (tid & 7) ^ (srow & 7);
  const f16* asrc[SA];
  const f16* bsrc[SB];
#pragma unroll
  for (int s = 0; s < SA; s++) {
    int row = m0 + s * 64 + srow;
    if (gl) row = gl[row < Meff ? row : Meff - 1];  // clamp: garbage rows never stored
    asrc[s] = p.A + aoff + (long)row * p.a_row + soct * 8;
  }
#pragma unroll
  for (int s = 0; s < SB; s++)
    bsrc[s] = p.Bm + boff + (long)(n0 + s * 64 + srow) * p.b_nstr + soct * 8;

  f32x4 acc[FM][FN] = {};

  auto stage = [&](f16* Ad, f16* Bd, int k0) {
#pragma unroll
    for (int s = 0; s < SA; s++) g2l16(asrc[s] + k0, &Ad[(s * 512 + tid) * 8]);
#pragma unroll
    for (int s = 0; s < SB; s++) g2l16(bsrc[s] + k0, &Bd[(s * 512 + tid) * 8]);
  };
  auto compute = [&](const f16* As, const f16* Bs) {
    half8 af[2][FM], bf[2][FN];
#pragma unroll
    for (int kk = 0; kk < 2; kk++) {
#pragma unroll
      for (int i = 0; i < FM; i++) {
        int r = wm + i * 16 + lo;
        af[kk][i] = *(const half8*)&As[r * 64 + ((kk * 4 + q) ^ (r & 7)) * 8];
      }
#pragma unroll
      for (int j = 0; j < FN; j++) {
        int n = wn + j * 16 + lo;
        bf[kk][j] = *(const half8*)&Bs[n * 64 + ((kk * 4 + q) ^ (n & 7)) * 8];
      }
    }
#pragma unroll
    for (int kk = 0; kk < 2; kk++)
#pragma unroll
      for (int i = 0; i < FM; i++)
#pragma unroll
        for (int j = 0; j < FN; j++)
          acc[i][j] = __builtin_amdgcn_mfma_f32_16x16x32_f16(af[kk][i], bf[kk][j], acc[i][j], 0, 0, 0);
  };

  // 2-phase pipeline: stage(next) issued before compute(cur); one barrier per K-step.
  stage(A0, B0, kb);
  __syncthreads();
  for (int k0 = kb; k0 < kEnd; k0 += 128) {
    if (k0 + 64 < kEnd) stage(A1, B1, k0 + 64);
    compute(A0, B0);
    __syncthreads();
    if (k0 + 64 < kEnd) {
      if (k0 + 128 < kEnd) stage(A0, B0, k0 + 128);
      compute(A1, B1);
      __syncthreads();
    }
  }

#pragma unroll
  for (int i = 0; i < FM; i++) {
#pragma unroll
    for (int j = 0; j < FN; j++) {
      int col = n0 + wn + j * 16 + lo;
      if (p.c_tr) {  // transposed f16 store: 4 consecutive rows -> one 8B store
        int row0 = m0 + wm + i * 16 + q * 4;
        union { f16 h[4]; uint2 u; } o;
#pragma unroll
        for (int r = 0; r < 4; r++) {
          float v = acc[i][j][r];
          if (p.bias) v += p.bias[biasoff + col];
          v *= p.alpha;
          o.h[r] = (f16)v;
        }
        *(uint2*)&p.Ch[coff + (long)col * p.c_row + row0] = o.u;
      } else {
#pragma unroll
        for (int r = 0; r < 4; r++) {
          int row = m0 + wm + i * 16 + q * 4 + r;
          if (row < Meff) {
            long rr = gl ? (long)gl[row] : (long)row;
            float v = acc[i][j][r];
            if (p.bias) v += p.bias[biasoff + col];
            v *= p.alpha;
            if (p.res) v += p.res[roff + rr * p.res_row + col];
            if (p.gelu) v = 0.5f * v * (1.0f + erff(v * 0.70710678118654752f));
            long ci = coff + rr * p.c_row + col;
            if (p.Cf) p.Cf[ci] = v;
            else p.Ch[ci] = (f16)v;
          }
        }
      }
    }
  }
}

template <int BM, int BN>
__global__ __launch_bounds__(512) void gemm_t(GemmP p) {
  __shared__ f16 A0[BM * 64], A1[BM * 64], B0[BN * 64], B1[BN * 64];
  int l = xcd_swz(blockIdx.x, gridDim.x);
  int bx = l % p.gx;
  int r = l / p.gx;
  int by = r % p.gy;
  int bz = r / p.gy;
  gemm_body<BM, BN>(p, bx, by, bz, A0, A1, B0, B1);
}

// fused Q/K/V projections: one flat grid, block ranges per sub-GEMM (128x128 tiles)
struct Multi3P {
  GemmP g0, g1, g2;
  int n0, n1;
  int gx0, gy0, gx1, gy1, gx2, gy2;
};

__global__ __launch_bounds__(512) void gemm_qkv(Multi3P mp) {
  __shared__ f16 A0[128 * 64], A1[128 * 64], B0[128 * 64], B1[128 * 64];
  int fb = xcd_swz(blockIdx.x, gridDim.x);
  if (fb < mp.n0) {
    gemm_body<128, 128>(mp.g0, fb % mp.gx0, (fb / mp.gx0) % mp.gy0, fb / (mp.gx0 * mp.gy0),
                        A0, A1, B0, B1);
    return;
  }
  fb -= mp.n0;
  if (fb < mp.n1) {
    gemm_body<128, 128>(mp.g1, fb % mp.gx1, (fb / mp.gx1) % mp.gy1, fb / (mp.gx1 * mp.gy1),
                        A0, A1, B0, B1);
    return;
  }
  fb -= mp.n1;
  gemm_body<128, 128>(mp.g2, fb % mp.gx2, (fb / mp.gx2) % mp.gy2, fb / (mp.gx2 * mp.gy2),
                      A0, A1, B0, B1);
}

extern "C" void kernel_launch(void* const* d_in, const int* in_sizes, int n_in,
                              void* d_out, int out_size, void* d_ws, size_t ws_size,
                              hipStream_t stream) {
  const float* concated = (const float*)d_in[0];
  const float* gen      = (const float*)d_in[1];
  const float* mask     = (const float*)d_in[2];
  const float* ln_g     = (const float*)d_in[3];
  const float* ln_b     = (const float*)d_in[4];
  const float* wq = (const float*)d_in[5];  const float* bq = (const float*)d_in[6];
  const float* wk = (const float*)d_in[7];  const float* bk = (const float*)d_in[8];
  const float* wv = (const float*)d_in[9];  const float* bv = (const float*)d_in[10];
  const float* wo = (const float*)d_in[11]; const float* bo = (const float*)d_in[12];
  const float* gw = (const float*)d_in[13]; const float* gb = (const float*)d_in[14];
  const float* w1 = (const float*)d_in[15]; const float* b1 = (const float*)d_in[16];
  const float* w2 = (const float*)d_in[17]; const float* b2 = (const float*)d_in[18];
  float* out = (float*)d_out;

  size_t off = 0;
  auto alloc = [&](size_t bytes) -> void* {
    void* p = (char*)d_ws + off;
    off += (bytes + 255) & ~(size_t)255;
    return p;
  };
  f16* wq_t  = (f16*)alloc((size_t)kH * kH * 2);       // [N][K]
  f16* wk_t  = (f16*)alloc((size_t)kH * kH * 2);
  f16* wv_t  = (f16*)alloc((size_t)kH * kH * 2);
  f16* wo_t  = (f16*)alloc((size_t)kH * kH * 2);
  f16* w1_t  = (f16*)alloc((size_t)kE * kH * kDFF * 2);  // [E][DFF][H]
  f16* w2_t  = (f16*)alloc((size_t)kE * kDFF * kH * 2);  // [E][H][DFF]
  f16* lnc_h = (f16*)alloc((size_t)kB * kSK * kH * 2);
  f16* lng_h = (f16*)alloc((size_t)kTok * kH * 2);
  f16* q_h   = (f16*)alloc((size_t)kTok * kH * 2);
  f16* k_h   = (f16*)alloc((size_t)kB * kSK * kH * 2);
  f16* v_t   = (f16*)alloc((size_t)kB * kSK * kH * 2);   // [b][h][d][sk]
  f16* ctx_h = (f16*)alloc((size_t)kTok * kH * 2);
  float* ca_f   = (float*)alloc((size_t)kTok * kH * 4);
  float* lnca_f = (float*)alloc((size_t)kTok * kH * 4);
  f16* lnca_h   = (f16*)alloc((size_t)kTok * kH * 2);
  f16* h1_h     = (f16*)alloc((size_t)kTok * kDFF * 2);
  float* part_f = (float*)alloc((size_t)4 * kTok * kH * 4);
  int* cnt_d    = (int*)alloc(kE * 4);
  int* list_d   = (int*)alloc((size_t)kE * kTok * 4);
  int* eid_d    = (int*)alloc((size_t)kTok * 4);

  // ---- all weight transpose-converts fp32 [K][N] -> fp16 [N][K] (one launch) ----
  {
    TrAllP tp{w1, w2, wq, wk, wv, wo, w1_t, w2_t, wq_t, wk_t, wv_t, wo_t};
    tr_all<<<dim3(1024, 1, 17), 256, 0, stream>>>(tp);
  }

  // ---- LayerNorms of both inputs (one launch) ----
  ln2_kernel<<<kB * kSK + kTok, 256, 0, stream>>>(concated, gen, ln_g, ln_b,
                                                  lnc_h, lng_h, kB * kSK);

  // ---- fused Q/K/V projections (one launch, 640 blocks at 128x128, 8 waves) ----
  {
    Multi3P mp{};
    GemmP& pq = mp.g0;
    pq.A = lng_h; pq.a_row = kH; pq.Bm = wq_t; pq.b_nstr = kH;
    pq.Ch = q_h; pq.c_row = kH; pq.bias = bq; pq.alpha = 0.125f;
    pq.M = kTok; pq.N = kH; pq.K = kH; pq.zdiv = 1;
    GemmP& pk = mp.g1;
    pk.A = lnc_h; pk.a_row = kH; pk.Bm = wk_t; pk.b_nstr = kH;
    pk.Ch = k_h; pk.c_row = kH; pk.bias = bk; pk.alpha = 1.0f;
    pk.M = kB * kSK; pk.N = kH; pk.K = kH; pk.zdiv = 1;
    GemmP& pv = mp.g2;
    pv.A = lnc_h; pv.a_row = kH; pv.a_z1 = (long)kSK * kH;
    pv.Bm = wv_t; pv.b_nstr = kH;
    pv.Ch = v_t; pv.c_row = kSK; pv.c_z1 = (long)kH * kSK; pv.c_tr = 1;
    pv.bias = bv; pv.alpha = 1.0f;
    pv.M = kSK; pv.N = kH; pv.K = kH; pv.zdiv = 1;
    mp.gx0 = kH / 128; mp.gy0 = kTok / 128;        mp.n0 = mp.gx0 * mp.gy0;       // 128
    mp.gx1 = kH / 128; mp.gy1 = (kB * kSK) / 128;  mp.n1 = mp.gx1 * mp.gy1;       // 256
    mp.gx2 = kH / 128; mp.gy2 = kSK / 128;                                         // x8, z=4
    int ntot = mp.n0 + mp.n1 + mp.gx2 * mp.gy2 * kB;                               // 640
    gemm_qkv<<<dim3(ntot), 512, 0, stream>>>(mp);
  }
  // ---- fused flash attention -> ctx_h (1D grid, XCD swizzle) ----
  flash_kernel<<<dim3((kSQ / 64) * kB * kHeads), 256, 0, stream>>>(q_h, k_h, v_t, mask, ctx_h);
  // ---- ca_out = ctx @ wo^T + bo + gen (fp32 out) ----
  {
    GemmP p{}; p.A = ctx_h; p.a_row = kH;
    p.Bm = wo_t; p.b_nstr = kH;
    p.Cf = ca_f; p.c_row = kH; p.bias = bo;
    p.res = gen; p.res_row = kH;
    p.alpha = 1.0f; p.M = kTok; p.N = kH; p.K = kH; p.zdiv = 1;
    p.gx = kH / 64; p.gy = kTok / 64;
    gemm_t<64, 64><<<dim3(p.gx * p.gy), 512, 0, stream>>>(p);
  }
  // ---- ln_ca (fp32 + fp16) + zero router cursors ----
  ln_kernel<<<kTok, 256, 0, stream>>>(ca_f, ln_g, ln_b, lnca_h, lnca_f, cnt_d);
  // ---- router + expert bucketing ----
  router_kernel<<<kTok, 64, 0, stream>>>(ca_f, gw, gb, cnt_d, list_d, eid_d);
  // ---- FFN1: h1 = gelu(ln_ca @ w1[e] + b1[e]) ; 128x128 tile, 8 waves ----
  {
    GemmP p{}; p.A = lnca_h; p.a_row = kH;
    p.Bm = w1_t; p.b_nstr = kH; p.b_z2 = (long)kH * kDFF;
    p.Ch = h1_h; p.c_row = kDFF; p.bias = b1; p.bias_z = kDFF;
    p.alpha = 1.0f; p.gelu = 1; p.M = kTok; p.N = kDFF; p.K = kH; p.zdiv = 1;
    p.glist = list_d; p.cnt = cnt_d;
    p.gx = kDFF / 128; p.gy = kTok / 128;
    gemm_t<128, 128><<<dim3(p.gx * p.gy * kE), 512, 0, stream>>>(p);
  }
  // ---- FFN2: part[s] = h1 @ w2[e] (split-K x4, fp32 partials, no atomics) ----
  {
    GemmP p{}; p.A = h1_h; p.a_row = kDFF;
    p.Bm = w2_t; p.b_nstr = kDFF; p.b_z2 = (long)kDFF * kH;
    p.Cf = part_f; p.c_row = kH; p.c_split = (long)kTok * kH;
    p.alpha = 1.0f; p.ksplit = 4;
    p.M = kTok; p.N = kH; p.K = kDFF; p.zdiv = 1;
    p.glist = list_d; p.cnt = cnt_d;
    p.gx = kH / 128; p.gy = kTok / 128;
    gemm_t<128, 128><<<dim3(p.gx * p.gy * kE * 4), 512, 0, stream>>>(p);
  }
  // ---- reduce: out = sum(part) + b2[eid] + lnca ----
  ffn2_reduce<<<kTok, 256, 0, stream>>>(part_f, lnca_f, b2, eid_d, out);
}